// Round 2
// baseline (1255.382 us; speedup 1.0000x reference)
//
#include <hip/hip_runtime.h>

// Problem constants
#define Bq 4
#define Tq 1024
#define Cq 1024
#define Hq 16
#define Dq 64
#define Fq 4096
#define Lq 4
#define BT (Bq*Tq)

typedef __attribute__((ext_vector_type(8))) __bf16 bf16x8;
typedef __attribute__((ext_vector_type(4))) float  floatx4;

__device__ __forceinline__ unsigned short f2bf(float f) {
  unsigned int u = __builtin_bit_cast(unsigned int, f);
  u = (u + 0x7FFFu + ((u >> 16) & 1u)) >> 16;   // RNE
  return (unsigned short)u;
}

// async global->LDS, 16B per lane; lds ptr must be wave-uniform (HW adds lane*16)
__device__ __forceinline__ void gld_lds16(const void* g, void* lds) {
  __builtin_amdgcn_global_load_lds(
      (const __attribute__((address_space(1))) unsigned int*)g,
      (__attribute__((address_space(3))) unsigned int*)lds, 16, 0, 0);
}

// partial-drain barrier used by the legacy 128^2 kernel
__device__ __forceinline__ void barrier_vmcnt4() {
  asm volatile("s_waitcnt vmcnt(4)\n\ts_barrier" ::: "memory");
}

// barriers for the 256^2 8-phase kernel
__device__ __forceinline__ void bar() {
  asm volatile("s_barrier" ::: "memory");
}
// trailing barrier: force this wave's ds_reads retired before any wave can
// issue the DMA that overwrites the region those reads touched.
__device__ __forceinline__ void bar_lgkm() {
  asm volatile("s_waitcnt lgkmcnt(0)\n\ts_barrier" ::: "memory");
}
__device__ __forceinline__ void bar_vm6() {
  asm volatile("s_waitcnt vmcnt(6)\n\ts_barrier" ::: "memory");
}
__device__ __forceinline__ void bar_vm0() {
  asm volatile("s_waitcnt vmcnt(0)\n\ts_barrier" ::: "memory");
}

// ---------------- embed: x = concat(emb[acts], dur) + pos ----------------
__global__ __launch_bounds__(256) void embed_kernel(
    const int* __restrict__ acts, const float* __restrict__ dur,
    const float* __restrict__ emb, const float* __restrict__ pos,
    float* __restrict__ x)
{
  int tok = blockIdx.x;
  int t = tok & (Tq-1);
  int a = acts[tok];
  const float* er = emb + (size_t)a * (Cq-1);
  const float* pr = pos + (size_t)t * Cq;
  float* xr = x + (size_t)tok * Cq;
  float dv = dur[tok];
  for (int c = threadIdx.x; c < Cq; c += 256) {
    float v = (c < Cq-1) ? er[c] : dv;
    xr[c] = v + pr[c];
  }
}

// ---------------- rmsnorm -> bf16 ----------------
__global__ __launch_bounds__(256) void rmsnorm_kernel(
    const float* __restrict__ x, const float* __restrict__ g,
    unsigned short* __restrict__ h)
{
  int tok = blockIdx.x, tid = threadIdx.x;
  const float4* xr = (const float4*)(x + (size_t)tok * Cq);
  float4 v = xr[tid];
  float ss = v.x*v.x + v.y*v.y + v.z*v.z + v.w*v.w;
  #pragma unroll
  for (int s = 32; s >= 1; s >>= 1) ss += __shfl_xor(ss, s, 64);
  __shared__ float ws4[4];
  if ((tid & 63) == 0) ws4[tid >> 6] = ss;
  __syncthreads();
  float tot = ws4[0] + ws4[1] + ws4[2] + ws4[3];
  float r = rsqrtf(tot * (1.0f/(float)Cq) + 1.1920928955078125e-07f);
  float4 gv = ((const float4*)g)[tid];
  unsigned short o4[4] = { f2bf(v.x*r*gv.x), f2bf(v.y*r*gv.y),
                           f2bf(v.z*r*gv.z), f2bf(v.w*r*gv.w) };
  *(uint2*)(h + (size_t)tok*Cq + tid*4) = *(const uint2*)o4;
}

// ---------------- fused per-layer weight prep: all 6 transposes in 1 launch ----------------
__global__ void prep_layer_kernel(
    const float* __restrict__ Wq, const float* __restrict__ Wk,
    const float* __restrict__ Wv, const float* __restrict__ Wo,
    const float* __restrict__ W1, const float* __restrict__ W2,
    unsigned short* __restrict__ wqkvl, unsigned short* __restrict__ wol,
    unsigned short* __restrict__ w1l,   unsigned short* __restrict__ w2l)
{
  __shared__ float tile[32][33];
  int z = blockIdx.x;
  const float* in; unsigned short* out;
  int R, Cc, tx, ty;
  if (z < 3072) {
    int i = z >> 10, t = z & 1023;
    int hh = t >> 6, rem = t & 63;
    ty = rem >> 1; tx = rem & 1;
    const float* w = (i == 0) ? Wq : (i == 1) ? Wk : Wv;
    in = w + (size_t)hh * Cq * Dq;
    out = wqkvl + (size_t)i * 1024 * 1024 + (size_t)hh * 64 * 1024;
    R = 1024; Cc = 64;
  } else if (z < 4096) {
    int t = z - 3072;
    tx = t & 31; ty = t >> 5;
    in = Wo; out = wol; R = 1024; Cc = 1024;
  } else if (z < 8192) {
    int t = z - 4096;
    tx = t & 127; ty = t >> 7;
    in = W1; out = w1l; R = 1024; Cc = 4096;
  } else {
    int t = z - 8192;
    tx = t & 31; ty = t >> 5;
    in = W2; out = w2l; R = 4096; Cc = 1024;
  }
  int c0 = tx * 32, r0 = ty * 32;
  int lx = threadIdx.x, ly = threadIdx.y;  // 32 x 8
  #pragma unroll
  for (int i = 0; i < 32; i += 8)
    tile[ly+i][lx] = in[(size_t)(r0+ly+i)*Cc + c0 + lx];
  __syncthreads();
  #pragma unroll
  for (int i = 0; i < 32; i += 8)
    out[(size_t)(c0+ly+i)*R + r0 + lx] = f2bf(tile[lx][ly+i]);
}

// ---------------- legacy 128^2 GEMM (Wo: EPI 2, FF2: EPI 3) ----------------
template <int EPI>
__global__ __launch_bounds__(256)
void gemm_bt_kernel(const unsigned short* __restrict__ A, int lda,
                    const unsigned short* __restrict__ Bt, int ldb,
                    int KS,
                    unsigned short* __restrict__ outB, int ldc,
                    unsigned short* __restrict__ vT,
                    float* __restrict__ outF, int ldf,
                    const float* __restrict__ bias)
{
  __shared__ unsigned short lds_a[3*4096];
  __shared__ unsigned short lds_b[3*4096];
  int tid = threadIdx.x;
  int lane = tid & 63, wv = tid >> 6;
  int lane15 = lane & 15, laneh = lane >> 4;
  int m0 = blockIdx.y * 128, n0 = blockIdx.x * 128;
  int wm = wv & 1, wn = wv >> 1;

  floatx4 acc[4][4];
  #pragma unroll
  for (int i = 0; i < 4; i++)
    #pragma unroll
    for (int j = 0; j < 4; j++) acc[i][j] = (floatx4){0.f,0.f,0.f,0.f};

  int seg0 = (wv*2+0)*64 + lane;
  int seg1 = (wv*2+1)*64 + lane;
  int ra0 = seg0 >> 2, ca0 = ((seg0 & 3) ^ (ra0 & 3)) * 8;
  int ra1 = seg1 >> 2, ca1 = ((seg1 & 3) ^ (ra1 & 3)) * 8;
  const unsigned short* a_src0 = A  + (size_t)(m0+ra0)*lda + ca0;
  const unsigned short* a_src1 = A  + (size_t)(m0+ra1)*lda + ca1;
  const unsigned short* b_src0 = Bt + (size_t)(n0+ra0)*ldb + ca0;
  const unsigned short* b_src1 = Bt + (size_t)(n0+ra1)*ldb + ca1;
  unsigned short* a_dst0 = &lds_a[(wv*2+0)*512];
  unsigned short* a_dst1 = &lds_a[(wv*2+1)*512];
  unsigned short* b_dst0 = &lds_b[(wv*2+0)*512];
  unsigned short* b_dst1 = &lds_b[(wv*2+1)*512];

  int sx = (laneh ^ (lane15 & 3)) * 8;

  int kbeg = (EPI == 3) ? blockIdx.z * KS : 0;
  int nIter = KS >> 5;

  auto stage = [&](int k0, int buf) {
    int off = buf * 4096;
    gld_lds16(a_src0 + k0, a_dst0 + off);
    gld_lds16(a_src1 + k0, a_dst1 + off);
    gld_lds16(b_src0 + k0, b_dst0 + off);
    gld_lds16(b_src1 + k0, b_dst1 + off);
  };

  stage(kbeg, 0);
  stage(kbeg + 32, 1);
  int cb = 0, pb = 2;
  for (int it = 0; it < nIter; ++it) {
    barrier_vmcnt4();
    if (it + 2 < nIter) stage(kbeg + (it+2)*32, pb);
    const unsigned short* la = &lds_a[cb*4096];
    const unsigned short* lb = &lds_b[cb*4096];
    bf16x8 af[4], bf[4];
    #pragma unroll
    for (int i = 0; i < 4; i++)
      af[i] = *(const bf16x8*)&la[(wm*64 + i*16 + lane15)*32 + sx];
    #pragma unroll
    for (int j = 0; j < 4; j++)
      bf[j] = *(const bf16x8*)&lb[(wn*64 + j*16 + lane15)*32 + sx];
    #pragma unroll
    for (int i = 0; i < 4; i++)
      #pragma unroll
      for (int j = 0; j < 4; j++)
        acc[i][j] = __builtin_amdgcn_mfma_f32_16x16x32_bf16(af[i], bf[j], acc[i][j], 0, 0, 0);
    cb = (cb == 2) ? 0 : cb + 1;
    pb = (pb == 2) ? 0 : pb + 1;
  }

  float* outFz = (EPI == 3) ? outF + (size_t)blockIdx.z * BT * Cq : outF;

  #pragma unroll
  for (int i = 0; i < 4; i++) {
    int row = m0 + wm*64 + i*16 + laneh*4;
    #pragma unroll
    for (int j = 0; j < 4; j++) {
      int col = n0 + wn*64 + j*16 + lane15;
      #pragma unroll
      for (int r = 0; r < 4; r++) {
        float v = acc[i][j][r];
        int rr = row + r;
        if constexpr (EPI == 0) {
          if (col < 2048) {
            outB[(size_t)rr*ldc + col] = f2bf(v);
          } else {
            int b = rr >> 10, t = rr & (Tq-1);
            int hd = col - 2048, hh = hd >> 6, d = hd & 63;
            vT[(((size_t)b*Hq + hh)*Dq + d)*Tq + t] = f2bf(v);
          }
        } else if constexpr (EPI == 1) {
          float z = v + bias[col];
          float u = 0.79788456080286536f * (z + 0.044715f * z*z*z);
          float t = 1.f - 2.f / (__expf(2.f*u) + 1.f);
          float gl = 0.5f * z * (1.f + t);
          outB[(size_t)rr*ldc + col] = f2bf(gl);
        } else if constexpr (EPI == 2) {
          outF[(size_t)rr*ldf + col] += v + bias[col];
        } else {
          outFz[(size_t)rr*ldf + col] = v;
        }
      }
    }
  }
}

// ---------------- 256^2 8-phase GEMM (HK-style schedule in plain HIP) -------
// C(M,N) = A(M,K) @ Bt(N,K)^T, bf16 in, fp32 acc. BM=BN=256, BK=64,
// 512 threads = 8 waves (wm in {0,1} x wn in {0..3}); interleaved wave->row
// mapping (row = fh*128 + ii*32 + wm*16 + lane15) makes each phase's LDS
// region uniform across waves:
//   P1=(A-lo,B-lo)  P2=(A-lo,B-hi)  P3=(A-hi,B-hi)  P4=(A-hi,B-lo)
// A-frags persist P1->P2 / P3->P4; B-frags persist P2->P3; B-lo re-read at P4.
// Staging: one half-tile (2x global_load_lds dwordx4 per thread) per phase:
//   P1: B-lo(t+1)   P2: A-lo(t+2)   P3: B-hi(t+2)   P4: A-hi(t+2)
// One counted wait per K-tile: vmcnt(6) at P4 (3 half-tiles stay in flight
// across every tile boundary; never drains to 0 in the main loop).
// Each phase ends with s_waitcnt lgkmcnt(0)+s_barrier: guarantees a region's
// ds_reads are retired >=1 barrier before the DMA that overwrites it issues.
// LDS layout [256][64] bf16 per matrix per buffer; full 8-period XOR swizzle
// (granule g of row r holds global granule g^(r&7)) applied on the GLOBAL
// source address (global_load_lds dest must stay linear).
// EPI 0: qkv scatter; EPI 1: gelu->bf16.
template <int EPI>
__global__ __launch_bounds__(512, 2)
void gemm256_kernel(const unsigned short* __restrict__ A, int lda,
                    const unsigned short* __restrict__ Bt, int ldb,
                    int KS,
                    unsigned short* __restrict__ outB, int ldc,
                    unsigned short* __restrict__ vT,
                    const float* __restrict__ bias)
{
  __shared__ unsigned short lds_a[2][256*64];
  __shared__ unsigned short lds_b[2][256*64];
  const int tid = threadIdx.x;
  const int lane = tid & 63, wv = tid >> 6;
  const int lane15 = lane & 15, laneh = lane >> 4;
  const int wm = wv & 1, wn = wv >> 1;      // 2 x 4 waves

  // XCD-aware bijective block swizzle (all grids used are %8==0)
  const int gx = gridDim.x, gy = gridDim.y;
  const int nwg = gx * gy;
  int wg = (int)blockIdx.y * gx + (int)blockIdx.x;
  if ((nwg & 7) == 0) wg = (wg & 7) * (nwg >> 3) + (wg >> 3);
  const int tn = wg % gx;
  const int tm = wg / gx;
  const int m0 = tm * 256, n0 = tn * 256;
  const int nT = KS >> 6;

  // staging source (pre-swizzled global granule)
  const int rowS = tid >> 3;
  const int gsw  = ((tid & 7) ^ (rowS & 7)) * 8;
  const unsigned short* a_src = A  + (size_t)(m0 + rowS) * lda + gsw;
  const unsigned short* b_src = Bt + (size_t)(n0 + rowS) * ldb + gsw;

  auto stageA_lo = [&](int t, int b) {
    const unsigned short* s = a_src + t*64;
    gld_lds16(s,                    &lds_a[b][    0 + wv*512]);
    gld_lds16(s + (size_t)64*lda,   &lds_a[b][ 4096 + wv*512]);
  };
  auto stageA_hi = [&](int t, int b) {
    const unsigned short* s = a_src + t*64 + (size_t)128*lda;
    gld_lds16(s,                    &lds_a[b][ 8192 + wv*512]);
    gld_lds16(s + (size_t)64*lda,   &lds_a[b][12288 + wv*512]);
  };
  auto stageB_lo = [&](int t, int b) {
    const unsigned short* s = b_src + t*64;
    gld_lds16(s,                    &lds_b[b][    0 + wv*512]);
    gld_lds16(s + (size_t)64*ldb,   &lds_b[b][ 4096 + wv*512]);
  };
  auto stageB_hi = [&](int t, int b) {
    const unsigned short* s = b_src + t*64 + (size_t)128*ldb;
    gld_lds16(s,                    &lds_b[b][ 8192 + wv*512]);
    gld_lds16(s + (size_t)64*ldb,   &lds_b[b][12288 + wv*512]);
  };

  // fragment read offsets (swizzled; r&7 == lane15&7 for all frag rows)
  const int soff0 = ((laneh)     ^ (lane15 & 7)) * 8;   // ks=0 granules 0..3
  const int soff1 = ((4 + laneh) ^ (lane15 & 7)) * 8;   // ks=1 granules 4..7
  const int arow = (wm*16 + lane15) * 64;
  const int brow = (wn*16 + lane15) * 64;

  floatx4 acc[8][4];
  #pragma unroll
  for (int i = 0; i < 8; i++)
    #pragma unroll
    for (int j = 0; j < 4; j++) acc[i][j] = (floatx4){0.f,0.f,0.f,0.f};

  bf16x8 af[4][2], bfr[2][2];

  // prologue: tile0 fully + AL(1), BH(1), AH(1); retire tile0, leave 6 loads.
  stageA_lo(0,0); stageB_lo(0,0); stageA_hi(0,0); stageB_hi(0,0);
  if (nT > 1) { stageA_lo(1,1); stageB_hi(1,1); stageA_hi(1,1); }
  bar_vm6();

  for (int t = 0; t < nT; ++t) {
    const int buf = t & 1;
    const unsigned short* la = &lds_a[buf][0];
    const unsigned short* lb = &lds_b[buf][0];

    // ---- P1: (A-lo, B-lo) ----
    #pragma unroll
    for (int ii = 0; ii < 4; ii++) {
      af[ii][0] = *(const bf16x8*)&la[arow + ii*2048 + soff0];
      af[ii][1] = *(const bf16x8*)&la[arow + ii*2048 + soff1];
    }
    #pragma unroll
    for (int jj = 0; jj < 2; jj++) {
      bfr[jj][0] = *(const bf16x8*)&lb[brow + jj*4096 + soff0];
      bfr[jj][1] = *(const bf16x8*)&lb[brow + jj*4096 + soff1];
    }
    if (t + 1 < nT) stageB_lo(t+1, buf^1);
    bar();
    __builtin_amdgcn_s_setprio(1);
    #pragma unroll
    for (int ks = 0; ks < 2; ks++)
      #pragma unroll
      for (int ii = 0; ii < 4; ii++)
        #pragma unroll
        for (int jj = 0; jj < 2; jj++)
          acc[ii][jj] = __builtin_amdgcn_mfma_f32_16x16x32_bf16(af[ii][ks], bfr[jj][ks], acc[ii][jj], 0, 0, 0);
    __builtin_amdgcn_s_setprio(0);
    bar_lgkm();

    // ---- P2: (A-lo, B-hi) — af reused ----
    #pragma unroll
    for (int jj = 0; jj < 2; jj++) {
      bfr[jj][0] = *(const bf16x8*)&lb[8192 + brow + jj*4096 + soff0];
      bfr[jj][1] = *(const bf16x8*)&lb[8192 + brow + jj*4096 + soff1];
    }
    if (t + 2 < nT) stageA_lo(t+2, buf);
    bar();
    __builtin_amdgcn_s_setprio(1);
    #pragma unroll
    for (int ks = 0; ks < 2; ks++)
      #pragma unroll
      for (int ii = 0; ii < 4; ii++)
        #pragma unroll
        for (int jj = 0; jj < 2; jj++)
          acc[ii][2+jj] = __builtin_amdgcn_mfma_f32_16x16x32_bf16(af[ii][ks], bfr[jj][ks], acc[ii][2+jj], 0, 0, 0);
    __builtin_amdgcn_s_setprio(0);
    bar_lgkm();

    // ---- P3: (A-hi, B-hi) — bfr reused ----
    #pragma unroll
    for (int ii = 0; ii < 4; ii++) {
      af[ii][0] = *(const bf16x8*)&la[8192 + arow + ii*2048 + soff0];
      af[ii][1] = *(const bf16x8*)&la[8192 + arow + ii*2048 + soff1];
    }
    if (t + 2 < nT) stageB_hi(t+2, buf);
    bar();
    __builtin_amdgcn_s_setprio(1);
    #pragma unroll
    for (int ks = 0; ks < 2; ks++)
      #pragma unroll
      for (int ii = 0; ii < 4; ii++)
        #pragma unroll
        for (int jj = 0; jj < 2; jj++)
          acc[4+ii][2+jj] = __builtin_amdgcn_mfma_f32_16x16x32_bf16(af[ii][ks], bfr[jj][ks], acc[4+ii][2+jj], 0, 0, 0);
    __builtin_amdgcn_s_setprio(0);
    bar_lgkm();

    // ---- P4: (A-hi, B-lo) — af reused, B-lo re-read ----
    #pragma unroll
    for (int jj = 0; jj < 2; jj++) {
      bfr[jj][0] = *(const bf16x8*)&lb[brow + jj*4096 + soff0];
      bfr[jj][1] = *(const bf16x8*)&lb[brow + jj*4096 + soff1];
    }
    if (t + 2 < nT) stageA_hi(t+2, buf);
    if (t < nT - 2) bar_vm6(); else bar_vm0();
    __builtin_amdgcn_s_setprio(1);
    #pragma unroll
    for (int ks = 0; ks < 2; ks++)
      #pragma unroll
      for (int ii = 0; ii < 4; ii++)
        #pragma unroll
        for (int jj = 0; jj < 2; jj++)
          acc[4+ii][jj] = __builtin_amdgcn_mfma_f32_16x16x32_bf16(af[ii][ks], bfr[jj][ks], acc[4+ii][jj], 0, 0, 0);
    __builtin_amdgcn_s_setprio(0);
    bar_lgkm();
  }

  #pragma unroll
  for (int i = 0; i < 8; i++) {
    int row = m0 + (i>>2)*128 + (i&3)*32 + wm*16 + laneh*4;
    #pragma unroll
    for (int j = 0; j < 4; j++) {
      int col = n0 + (j>>1)*128 + (j&1)*64 + wn*16 + lane15;
      #pragma unroll
      for (int r = 0; r < 4; r++) {
        float v = acc[i][j][r];
        int rr = row + r;
        if constexpr (EPI == 0) {
          if (col < 2048) {
            outB[(size_t)rr*ldc + col] = f2bf(v);
          } else {
            int b = rr >> 10, t = rr & (Tq-1);
            int hd = col - 2048, hh = hd >> 6, d = hd & 63;
            vT[(((size_t)b*Hq + hh)*Dq + d)*Tq + t] = f2bf(v);
          }
        } else {
          float z = v + bias[col];
          float u = 0.79788456080286536f * (z + 0.044715f * z*z*z);
          float tt = 1.f - 2.f / (__expf(2.f*u) + 1.f);
          float gl = 0.5f * z * (1.f + tt);
          outB[(size_t)rr*ldc + col] = f2bf(gl);
        }
      }
    }
  }
}

// ---------------- split-K reduce: x += p0 + p1 + bias ----------------
__global__ __launch_bounds__(256) void splitk_reduce_kernel(
    const float* __restrict__ p, float* __restrict__ x,
    const float* __restrict__ bias)
{
  size_t o = ((size_t)blockIdx.x * 256 + threadIdx.x) * 4;
  float4 a = *(const float4*)(p + o);
  float4 b = *(const float4*)(p + (size_t)BT*Cq + o);
  float4 xv = *(const float4*)(x + o);
  float4 bi = *(const float4*)(bias + (o & (Cq-1)));
  xv.x += a.x + b.x + bi.x;
  xv.y += a.y + b.y + bi.y;
  xv.z += a.z + b.z + bi.z;
  xv.w += a.w + b.w + bi.w;
  *(float4*)(x + o) = xv;
}

// ---------------- flash attention (causal), S^T form (R6-verified) ----------------
__global__ __launch_bounds__(256)
void attn_kernel(const unsigned short* __restrict__ qk,   // (BT,2048): q 0..1023, k 1024..2047
                 const unsigned short* __restrict__ vT,   // (B,H,D,T)
                 unsigned short* __restrict__ ob)         // (BT,1024)
{
  __shared__ unsigned short Ks [2][64*64];
  __shared__ unsigned short Vts[2][64*64];
  __shared__ unsigned short Ps [4*16*64];
  int tid = threadIdx.x, lane = tid & 63, wv = tid >> 6;
  int lane15 = lane & 15, laneh = lane >> 4;
  int blk = blockIdx.x;
  int p = blk & 7, bh = blk >> 3;
  int h = bh & (Hq-1), b = bh >> 4;
  size_t tokbase = (size_t)b * Tq;
  const unsigned short* Kbase = qk + tokbase*2048 + 1024 + h*64;
  const unsigned short* Vbase = vT + (size_t)bh * Dq * Tq;

  int so  = (laneh ^ (lane15 & 7)) * 8;
  int so32 = so ^ 32;
  unsigned short* Pw = &Ps[wv*1024];

  auto stage = [&](int j0, int buf) {
    #pragma unroll
    for (int i = 0; i < 2; i++) {
      int seg = (wv*2+i)*64 + lane;
      int row = seg >> 3;
      int col = ((seg & 7) ^ (row & 7)) * 8;
      gld_lds16(Kbase + (size_t)(j0+row)*2048 + col, &Ks [buf][(wv*2+i)*512]);
      gld_lds16(Vbase + (size_t)row*Tq + j0 + col,   &Vts[buf][(wv*2+i)*512]);
    }
  };

  for (int phase = 0; phase < 2; ++phase) {
    int qt = phase ? (15 - p) : p;
    int qrow0 = qt*64 + wv*16;
    bf16x8 qf0, qf1;
    {
      const unsigned short* qp = qk + (tokbase + qrow0 + lane15)*2048 + h*64 + laneh*8;
      qf0 = *(const bf16x8*)(qp);
      qf1 = *(const bf16x8*)(qp + 32);
    }
    floatx4 oacc[4];
    #pragma unroll
    for (int d = 0; d < 4; d++) oacc[d] = (floatx4){0.f,0.f,0.f,0.f};
    float mrow = -__builtin_inff(), lrow = 0.f;
    int nT = qt + 1;

    __syncthreads();
    stage(0, 0);
    for (int it = 0; it < nT; ++it) {
      __syncthreads();
      if (it + 1 < nT) stage((it+1)*64, (it+1) & 1);
      int buf = it & 1;
      int j0 = it*64;

      floatx4 sac[4];
      #pragma unroll
      for (int jt = 0; jt < 4; jt++) {
        int row = jt*16 + lane15;
        bf16x8 kf0 = *(const bf16x8*)&Ks[buf][row*64 + so];
        bf16x8 kf1 = *(const bf16x8*)&Ks[buf][row*64 + so32];
        sac[jt] = (floatx4){0.f,0.f,0.f,0.f};
        sac[jt] = __builtin_amdgcn_mfma_f32_16x16x32_bf16(kf0, qf0, sac[jt], 0, 0, 0);
        sac[jt] = __builtin_amdgcn_mfma_f32_16x16x32_bf16(kf1, qf1, sac[jt], 0, 0, 0);
      }
      if (j0 + 63 > qrow0) {
        int tokg = qrow0 + lane15;
        #pragma unroll
        for (int jt = 0; jt < 4; jt++)
          #pragma unroll
          for (int r = 0; r < 4; r++) {
            int kv = j0 + jt*16 + laneh*4 + r;
            sac[jt][r] = (kv <= tokg) ? sac[jt][r] * 0.125f : -__builtin_inff();
          }
      } else {
        #pragma unroll
        for (int jt = 0; jt < 4; jt++)
          #pragma unroll
          for (int r = 0; r < 4; r++) sac[jt][r] *= 0.125f;
      }
      float mx = sac[0][0];
      #pragma unroll
      for (int jt = 0; jt < 4; jt++)
        #pragma unroll
        for (int r = 0; r < 4; r++) mx = fmaxf(mx, sac[jt][r]);
      mx = fmaxf(mx, __shfl_xor(mx, 16, 64));
      mx = fmaxf(mx, __shfl_xor(mx, 32, 64));
      float mn = fmaxf(mrow, mx);
      float alpha = __expf(mrow - mn);
      float psum = 0.f;
      #pragma unroll
      for (int jt = 0; jt < 4; jt++)
        #pragma unroll
        for (int r = 0; r < 4; r++) {
          float pv = __expf(sac[jt][r] - mn);
          sac[jt][r] = pv;
          psum += pv;
        }
      psum += __shfl_xor(psum, 16, 64);
      psum += __shfl_xor(psum, 32, 64);
      lrow = lrow * alpha + psum;
      mrow = mn;
      #pragma unroll
      for (int dt = 0; dt < 4; dt++)
        #pragma unroll
        for (int r = 0; r < 4; r++) oacc[dt][r] *= alpha;

      #pragma unroll
      for (int jt = 0; jt < 4; jt++) {
        unsigned int p0 = (unsigned int)f2bf(sac[jt][0]) | ((unsigned int)f2bf(sac[jt][1]) << 16);
        unsigned int p1 = (unsigned int)f2bf(sac[jt][2]) | ((unsigned int)f2bf(sac[jt][3]) << 16);
        int slot = (jt*2 + (laneh >> 1)) ^ (lane15 & 7);
        *(uint2*)&Pw[lane15*64 + slot*8 + (laneh & 1)*4] = make_uint2(p0, p1);
      }
      bf16x8 pf0 = *(const bf16x8*)&Pw[lane15*64 + so];
      bf16x8 pf1 = *(const bf16x8*)&Pw[lane15*64 + so32];
      #pragma unroll
      for (int dt = 0; dt < 4; dt++) {
        int row = dt*16 + lane15;
        bf16x8 vf0 = *(const bf16x8*)&Vts[buf][row*64 + so];
        bf16x8 vf1 = *(const bf16x8*)&Vts[buf][row*64 + so32];
        oacc[dt] = __builtin_amdgcn_mfma_f32_16x16x32_bf16(vf0, pf0, oacc[dt], 0, 0, 0);
        oacc[dt] = __builtin_amdgcn_mfma_f32_16x16x32_bf16(vf1, pf1, oacc[dt], 0, 0, 0);
      }
    }
    float inv = 1.f / lrow;
    unsigned short* orow = ob + (tokbase + qrow0 + lane15)*Cq + h*64 + laneh*4;
    #pragma unroll
    for (int dt = 0; dt < 4; dt++) {
      unsigned int u0 = (unsigned int)f2bf(oacc[dt][0]*inv) | ((unsigned int)f2bf(oacc[dt][1]*inv) << 16);
      unsigned int u1 = (unsigned int)f2bf(oacc[dt][2]*inv) | ((unsigned int)f2bf(oacc[dt][3]*inv) << 16);
      *(uint2*)&orow[dt*16] = make_uint2(u0, u1);
    }
  }
}

// ---------------- lm head prep ----------------
__global__ __launch_bounds__(256) void lmw_prep_kernel(
    const float* __restrict__ lmW, unsigned short* __restrict__ lmWt,
    float* __restrict__ lmWcol)
{
  int idx = blockIdx.x * 256 + threadIdx.x;
  int n = idx & 63, k = idx >> 6;
  lmWt[(size_t)n*Cq + k] = f2bf(lmW[(size_t)k*65 + n]);
  if (idx < Cq) lmWcol[idx] = lmW[(size_t)idx*65 + 64];
}

// ---------------- head: MFMA logits + fused log-softmax + log-sigmoid(dur) ----------------
__global__ __launch_bounds__(64) void head_mfma_kernel(
    const float* __restrict__ x, const unsigned short* __restrict__ lmWt,
    const float* __restrict__ lmWcol, const float* __restrict__ lmb,
    float* __restrict__ out)
{
  int lane = threadIdx.x;
  int lane15 = lane & 15, laneh = lane >> 4;
  int tok0 = blockIdx.x * 16;

  floatx4 acc[4];
  #pragma unroll
  for (int jt = 0; jt < 4; jt++) acc[jt] = (floatx4){0.f,0.f,0.f,0.f};

  const float* xrow = x + (size_t)(tok0 + lane15) * Cq + laneh*8;
  const unsigned short* brow = lmWt + (size_t)lane15 * Cq + laneh*8;

  for (int k0 = 0; k0 < Cq; k0 += 32) {
    float4 a0 = *(const float4*)(xrow + k0);
    float4 a1 = *(const float4*)(xrow + k0 + 4);
    bf16x8 af;
    af[0] = (__bf16)a0.x; af[1] = (__bf16)a0.y; af[2] = (__bf16)a0.z; af[3] = (__bf16)a0.w;
    af[4] = (__bf16)a1.x; af[5] = (__bf16)a1.y; af[6] = (__bf16)a1.z; af[7] = (__bf16)a1.w;
    #pragma unroll
    for (int jt = 0; jt < 4; jt++) {
      bf16x8 bfv = *(const bf16x8*)(brow + (size_t)jt*16*Cq + k0);
      acc[jt] = __builtin_amdgcn_mfma_f32_16x16x32_bf16(af, bfv, acc[jt], 0, 0, 0);
    }
  }
  #pragma unroll
  for (int jt = 0; jt < 4; jt++) {
    float bias = lmb[jt*16 + lane15];
    #pragma unroll
    for (int r = 0; r < 4; r++) acc[jt][r] += bias;
  }
  #pragma unroll
  for (int r = 0; r < 4; r++) {
    float m = fmaxf(fmaxf(acc[0][r], acc[1][r]), fmaxf(acc[2][r], acc[3][r]));
    #pragma unroll
    for (int s = 1; s < 16; s <<= 1) m = fmaxf(m, __shfl_xor(m, s, 64));
    float se = 0.f;
    #pragma unroll
    for (int jt = 0; jt < 4; jt++) se += expf(acc[jt][r] - m);
    #pragma unroll
    for (int s = 1; s < 16; s <<= 1) se += __shfl_xor(se, s, 64);
    float lse = m + logf(se);
    int tok = tok0 + laneh*4 + r;
    float* orow = out + (size_t)tok * 65;
    #pragma unroll
    for (int jt = 0; jt < 4; jt++)
      orow[jt*16 + lane15] = acc[jt][r] - lse;
  }
  int t = lane >> 2, kq = (lane & 3) * 256;
  const float* xr2 = x + (size_t)(tok0 + t) * Cq + kq;
  const float* wc = lmWcol + kq;
  float s = 0.f;
  #pragma unroll 4
  for (int i = 0; i < 256; i += 4) {
    float4 xv = *(const float4*)(xr2 + i);
    float4 wv = *(const float4*)(wc + i);
    s += xv.x*wv.x + xv.y*wv.y + xv.z*wv.z + xv.w*wv.w;
  }
  s += __shfl_xor(s, 1, 64);
  s += __shfl_xor(s, 2, 64);
  if ((lane & 3) == 0) {
    float z = s + lmb[64];
    float ls = (z >= 0.f) ? -log1pf(expf(-z)) : (z - log1pf(expf(z)));
    out[(size_t)(tok0 + t) * 65 + 64] = ls;
  }
}

extern "C" void kernel_launch(void* const* d_in, const int* in_sizes, int n_in,
                              void* d_out, int out_size, void* d_ws, size_t ws_size,
                              hipStream_t stream) {
  const int*   acts = (const int*)  d_in[0];
  const float* dur  = (const float*)d_in[1];
  const float* emb  = (const float*)d_in[2];
  const float* pos  = (const float*)d_in[3];
  const float* Wq   = (const float*)d_in[4];
  const float* Wk   = (const float*)d_in[5];
  const float* Wv   = (const float*)d_in[6];
  const float* Wo   = (const float*)d_in[7];
  const float* bo   = (const float*)d_in[8];
  const float* W1   = (const float*)d_in[9];
  const float* b1   = (const float*)d_in[10];
  const float* W2   = (const float*)d_in[11];
  const float* b2   = (const float*)d_in[12];
  const float* g1   = (const float*)d_in[13];
  const float* g2   = (const float*)d_in[14];
  const float* lmW  = (const float*)d_in[15];
  const float* lmb  = (const float*)d_in[16];
  float* out = (float*)d_out;
  (void)in_sizes; (void)n_in; (void)out_size; (void)ws_size;

  char* w = (char*)d_ws;
  auto take = [&](size_t bytes) { char* p = w; w += (bytes + 255) & ~(size_t)255; return p; };
  unsigned short* qk  = (unsigned short*)take((size_t)BT*2048*2);
  unsigned short* vT  = (unsigned short*)take((size_t)Bq*Hq*Dq*Tq*2);
  unsigned short* ob  = (unsigned short*)take((size_t)BT*Cq*2);
  unsigned short* m1  = qk;                      // FF1 out aliases qk+vT+ob (32 MB)
  unsigned short* hb  = (unsigned short*)take((size_t)BT*Cq*2);
  float*          x   = (float*)take((size_t)BT*Cq*4);
  unsigned short* wqkvl = (unsigned short*)take((size_t)3072*Cq*2);
  unsigned short* wol   = (unsigned short*)take((size_t)Cq*Cq*2);
  unsigned short* w1l   = (unsigned short*)take((size_t)Fq*Cq*2);
  unsigned short* w2l   = (unsigned short*)take((size_t)Cq*Fq*2);
  unsigned short* lmWt  = (unsigned short*)take((size_t)64*Cq*2);
  float*          lmWcol= (float*)take((size_t)Cq*4);
  float*          part  = (float*)take((size_t)2*BT*Cq*4);   // split-K partials (32 MB)

  dim3 tb(32, 8);
  embed_kernel<<<BT, 256, 0, stream>>>(acts, dur, emb, pos, x);
  lmw_prep_kernel<<<256, 256, 0, stream>>>(lmW, lmWt, lmWcol);

  for (int l = 0; l < Lq; l++) {
    prep_layer_kernel<<<12288, tb, 0, stream>>>(
        Wq + (size_t)l*Hq*Cq*Dq, Wk + (size_t)l*Hq*Cq*Dq, Wv + (size_t)l*Hq*Cq*Dq,
        Wo + (size_t)l*Cq*Cq, W1 + (size_t)l*Cq*Fq, W2 + (size_t)l*Fq*Cq,
        wqkvl, wol, w1l, w2l);

    rmsnorm_kernel<<<BT, 256, 0, stream>>>(x, g1 + l*Cq, hb);
    gemm256_kernel<0><<<dim3(12,16), 512, 0, stream>>>(
        hb, Cq, wqkvl, Cq, Cq, qk, 2048, vT, nullptr);
    attn_kernel<<<Bq*Hq*8, 256, 0, stream>>>(qk, vT, ob);
    gemm_bt_kernel<2><<<dim3(8,32), 256, 0, stream>>>(
        ob, Cq, wol, Cq, Cq, nullptr, 0, nullptr, x, Cq, bo + l*Cq);
    rmsnorm_kernel<<<BT, 256, 0, stream>>>(x, g2 + l*Cq, hb);
    gemm256_kernel<1><<<dim3(16,16), 512, 0, stream>>>(
        hb, Cq, w1l, Cq, Cq, m1, Fq, nullptr, b1 + l*Fq);
    gemm_bt_kernel<3><<<dim3(8,32,2), 256, 0, stream>>>(
        m1, Fq, w2l, Fq, 2048, nullptr, 0, nullptr, part, Cq, nullptr);
    splitk_reduce_kernel<<<BT*Cq/1024, 256, 0, stream>>>(part, x, b2 + l*Cq);
  }
  head_mfma_kernel<<<BT/16, 64, 0, stream>>>(x, lmWt, lmWcol, lmb, out);
}

// Round 3
// 1251.998 us; speedup vs baseline: 1.0027x; 1.0027x over previous
//
#include <hip/hip_runtime.h>

// Problem constants
#define Bq 4
#define Tq 1024
#define Cq 1024
#define Hq 16
#define Dq 64
#define Fq 4096
#define Lq 4
#define BT (Bq*Tq)

typedef __attribute__((ext_vector_type(8))) __bf16 bf16x8;
typedef __attribute__((ext_vector_type(4))) float  floatx4;

__device__ __forceinline__ unsigned short f2bf(float f) {
  unsigned int u = __builtin_bit_cast(unsigned int, f);
  u = (u + 0x7FFFu + ((u >> 16) & 1u)) >> 16;   // RNE
  return (unsigned short)u;
}

// async global->LDS, 16B per lane; lds ptr must be wave-uniform (HW adds lane*16)
__device__ __forceinline__ void gld_lds16(const void* g, void* lds) {
  __builtin_amdgcn_global_load_lds(
      (const __attribute__((address_space(1))) unsigned int*)g,
      (__attribute__((address_space(3))) unsigned int*)lds, 16, 0, 0);
}

// partial-drain barrier used by the legacy 128^2 kernel (kept as-is; measured-good)
__device__ __forceinline__ void barrier_vmcnt4() {
  asm volatile("s_waitcnt vmcnt(4)\n\ts_barrier" ::: "memory");
}

// ---- sync primitives for the 256^2 8-phase kernel ----
// NO "memory" clobbers: a memory-clobbered asm acts as an IR-level fence and
// makes hipcc emit conservative full vmcnt(0) drains at every barrier,
// collapsing the counted-vmcnt pipeline (round-2 post-mortem: 2000 stall
// cycles/phase). Instead: raw s_barrier builtin + clobber-free waitcnt, both
// pinned with sched_barrier(0) so no instruction (incl. MFMA, ds_read, DMA
// issue) crosses them (rule #18).
__device__ __forceinline__ void sbar() {
  __builtin_amdgcn_sched_barrier(0);
  __builtin_amdgcn_s_barrier();
  __builtin_amdgcn_sched_barrier(0);
}
__device__ __forceinline__ void wait_lgkm0() {
  asm volatile("s_waitcnt lgkmcnt(0)");
  __builtin_amdgcn_sched_barrier(0);
}
__device__ __forceinline__ void wait_vm6() {
  asm volatile("s_waitcnt vmcnt(6)");
  __builtin_amdgcn_sched_barrier(0);
}
__device__ __forceinline__ void wait_vm0() {
  asm volatile("s_waitcnt vmcnt(0)");
  __builtin_amdgcn_sched_barrier(0);
}

// ---------------- embed: x = concat(emb[acts], dur) + pos ----------------
__global__ __launch_bounds__(256) void embed_kernel(
    const int* __restrict__ acts, const float* __restrict__ dur,
    const float* __restrict__ emb, const float* __restrict__ pos,
    float* __restrict__ x)
{
  int tok = blockIdx.x;
  int t = tok & (Tq-1);
  int a = acts[tok];
  const float* er = emb + (size_t)a * (Cq-1);
  const float* pr = pos + (size_t)t * Cq;
  float* xr = x + (size_t)tok * Cq;
  float dv = dur[tok];
  for (int c = threadIdx.x; c < Cq; c += 256) {
    float v = (c < Cq-1) ? er[c] : dv;
    xr[c] = v + pr[c];
  }
}

// ---------------- rmsnorm -> bf16 ----------------
__global__ __launch_bounds__(256) void rmsnorm_kernel(
    const float* __restrict__ x, const float* __restrict__ g,
    unsigned short* __restrict__ h)
{
  int tok = blockIdx.x, tid = threadIdx.x;
  const float4* xr = (const float4*)(x + (size_t)tok * Cq);
  float4 v = xr[tid];
  float ss = v.x*v.x + v.y*v.y + v.z*v.z + v.w*v.w;
  #pragma unroll
  for (int s = 32; s >= 1; s >>= 1) ss += __shfl_xor(ss, s, 64);
  __shared__ float ws4[4];
  if ((tid & 63) == 0) ws4[tid >> 6] = ss;
  __syncthreads();
  float tot = ws4[0] + ws4[1] + ws4[2] + ws4[3];
  float r = rsqrtf(tot * (1.0f/(float)Cq) + 1.1920928955078125e-07f);
  float4 gv = ((const float4*)g)[tid];
  unsigned short o4[4] = { f2bf(v.x*r*gv.x), f2bf(v.y*r*gv.y),
                           f2bf(v.z*r*gv.z), f2bf(v.w*r*gv.w) };
  *(uint2*)(h + (size_t)tok*Cq + tid*4) = *(const uint2*)o4;
}

// ---------------- fused per-layer weight prep: all 6 transposes in 1 launch ----------------
__global__ void prep_layer_kernel(
    const float* __restrict__ Wq, const float* __restrict__ Wk,
    const float* __restrict__ Wv, const float* __restrict__ Wo,
    const float* __restrict__ W1, const float* __restrict__ W2,
    unsigned short* __restrict__ wqkvl, unsigned short* __restrict__ wol,
    unsigned short* __restrict__ w1l,   unsigned short* __restrict__ w2l)
{
  __shared__ float tile[32][33];
  int z = blockIdx.x;
  const float* in; unsigned short* out;
  int R, Cc, tx, ty;
  if (z < 3072) {
    int i = z >> 10, t = z & 1023;
    int hh = t >> 6, rem = t & 63;
    ty = rem >> 1; tx = rem & 1;
    const float* w = (i == 0) ? Wq : (i == 1) ? Wk : Wv;
    in = w + (size_t)hh * Cq * Dq;
    out = wqkvl + (size_t)i * 1024 * 1024 + (size_t)hh * 64 * 1024;
    R = 1024; Cc = 64;
  } else if (z < 4096) {
    int t = z - 3072;
    tx = t & 31; ty = t >> 5;
    in = Wo; out = wol; R = 1024; Cc = 1024;
  } else if (z < 8192) {
    int t = z - 4096;
    tx = t & 127; ty = t >> 7;
    in = W1; out = w1l; R = 1024; Cc = 4096;
  } else {
    int t = z - 8192;
    tx = t & 31; ty = t >> 5;
    in = W2; out = w2l; R = 4096; Cc = 1024;
  }
  int c0 = tx * 32, r0 = ty * 32;
  int lx = threadIdx.x, ly = threadIdx.y;  // 32 x 8
  #pragma unroll
  for (int i = 0; i < 32; i += 8)
    tile[ly+i][lx] = in[(size_t)(r0+ly+i)*Cc + c0 + lx];
  __syncthreads();
  #pragma unroll
  for (int i = 0; i < 32; i += 8)
    out[(size_t)(c0+ly+i)*R + r0 + lx] = f2bf(tile[lx][ly+i]);
}

// ---------------- legacy 128^2 GEMM (Wo: EPI 2, FF2: EPI 3) ----------------
template <int EPI>
__global__ __launch_bounds__(256)
void gemm_bt_kernel(const unsigned short* __restrict__ A, int lda,
                    const unsigned short* __restrict__ Bt, int ldb,
                    int KS,
                    unsigned short* __restrict__ outB, int ldc,
                    unsigned short* __restrict__ vT,
                    float* __restrict__ outF, int ldf,
                    const float* __restrict__ bias)
{
  __shared__ unsigned short lds_a[3*4096];
  __shared__ unsigned short lds_b[3*4096];
  int tid = threadIdx.x;
  int lane = tid & 63, wv = tid >> 6;
  int lane15 = lane & 15, laneh = lane >> 4;
  int m0 = blockIdx.y * 128, n0 = blockIdx.x * 128;
  int wm = wv & 1, wn = wv >> 1;

  floatx4 acc[4][4];
  #pragma unroll
  for (int i = 0; i < 4; i++)
    #pragma unroll
    for (int j = 0; j < 4; j++) acc[i][j] = (floatx4){0.f,0.f,0.f,0.f};

  int seg0 = (wv*2+0)*64 + lane;
  int seg1 = (wv*2+1)*64 + lane;
  int ra0 = seg0 >> 2, ca0 = ((seg0 & 3) ^ (ra0 & 3)) * 8;
  int ra1 = seg1 >> 2, ca1 = ((seg1 & 3) ^ (ra1 & 3)) * 8;
  const unsigned short* a_src0 = A  + (size_t)(m0+ra0)*lda + ca0;
  const unsigned short* a_src1 = A  + (size_t)(m0+ra1)*lda + ca1;
  const unsigned short* b_src0 = Bt + (size_t)(n0+ra0)*ldb + ca0;
  const unsigned short* b_src1 = Bt + (size_t)(n0+ra1)*ldb + ca1;
  unsigned short* a_dst0 = &lds_a[(wv*2+0)*512];
  unsigned short* a_dst1 = &lds_a[(wv*2+1)*512];
  unsigned short* b_dst0 = &lds_b[(wv*2+0)*512];
  unsigned short* b_dst1 = &lds_b[(wv*2+1)*512];

  int sx = (laneh ^ (lane15 & 3)) * 8;

  int kbeg = (EPI == 3) ? blockIdx.z * KS : 0;
  int nIter = KS >> 5;

  auto stage = [&](int k0, int buf) {
    int off = buf * 4096;
    gld_lds16(a_src0 + k0, a_dst0 + off);
    gld_lds16(a_src1 + k0, a_dst1 + off);
    gld_lds16(b_src0 + k0, b_dst0 + off);
    gld_lds16(b_src1 + k0, b_dst1 + off);
  };

  stage(kbeg, 0);
  stage(kbeg + 32, 1);
  int cb = 0, pb = 2;
  for (int it = 0; it < nIter; ++it) {
    barrier_vmcnt4();
    if (it + 2 < nIter) stage(kbeg + (it+2)*32, pb);
    const unsigned short* la = &lds_a[cb*4096];
    const unsigned short* lb = &lds_b[cb*4096];
    bf16x8 af[4], bf[4];
    #pragma unroll
    for (int i = 0; i < 4; i++)
      af[i] = *(const bf16x8*)&la[(wm*64 + i*16 + lane15)*32 + sx];
    #pragma unroll
    for (int j = 0; j < 4; j++)
      bf[j] = *(const bf16x8*)&lb[(wn*64 + j*16 + lane15)*32 + sx];
    #pragma unroll
    for (int i = 0; i < 4; i++)
      #pragma unroll
      for (int j = 0; j < 4; j++)
        acc[i][j] = __builtin_amdgcn_mfma_f32_16x16x32_bf16(af[i], bf[j], acc[i][j], 0, 0, 0);
    cb = (cb == 2) ? 0 : cb + 1;
    pb = (pb == 2) ? 0 : pb + 1;
  }

  float* outFz = (EPI == 3) ? outF + (size_t)blockIdx.z * BT * Cq : outF;

  #pragma unroll
  for (int i = 0; i < 4; i++) {
    int row = m0 + wm*64 + i*16 + laneh*4;
    #pragma unroll
    for (int j = 0; j < 4; j++) {
      int col = n0 + wn*64 + j*16 + lane15;
      #pragma unroll
      for (int r = 0; r < 4; r++) {
        float v = acc[i][j][r];
        int rr = row + r;
        if constexpr (EPI == 0) {
          if (col < 2048) {
            outB[(size_t)rr*ldc + col] = f2bf(v);
          } else {
            int b = rr >> 10, t = rr & (Tq-1);
            int hd = col - 2048, hh = hd >> 6, d = hd & 63;
            vT[(((size_t)b*Hq + hh)*Dq + d)*Tq + t] = f2bf(v);
          }
        } else if constexpr (EPI == 1) {
          float z = v + bias[col];
          float u = 0.79788456080286536f * (z + 0.044715f * z*z*z);
          float t = 1.f - 2.f / (__expf(2.f*u) + 1.f);
          float gl = 0.5f * z * (1.f + t);
          outB[(size_t)rr*ldc + col] = f2bf(gl);
        } else if constexpr (EPI == 2) {
          outF[(size_t)rr*ldf + col] += v + bias[col];
        } else {
          outFz[(size_t)rr*ldf + col] = v;
        }
      }
    }
  }
}

// ---------------- 256^2 8-phase GEMM (HK-style schedule in plain HIP) -------
// Structure identical to round 2 (ledger-verified race-free, refcheck-passed);
// only the sync primitives changed: raw s_barrier + clobber-free counted
// waitcnt + sched_barrier(0) fences, so the compiler does not insert its own
// vmcnt(0) drains at the 8 barriers/K-tile. vmcnt(6) is waited BEFORE the
// P4 barrier (wait-then-barrier gives cross-wave DMA visibility).
// EPI 0: qkv scatter; EPI 1: gelu->bf16.
template <int EPI>
__global__ __launch_bounds__(512, 2)
void gemm256_kernel(const unsigned short* __restrict__ A, int lda,
                    const unsigned short* __restrict__ Bt, int ldb,
                    int KS,
                    unsigned short* __restrict__ outB, int ldc,
                    unsigned short* __restrict__ vT,
                    const float* __restrict__ bias)
{
  __shared__ unsigned short lds_a[2][256*64];
  __shared__ unsigned short lds_b[2][256*64];
  const int tid = threadIdx.x;
  const int lane = tid & 63, wv = tid >> 6;
  const int lane15 = lane & 15, laneh = lane >> 4;
  const int wm = wv & 1, wn = wv >> 1;      // 2 x 4 waves

  // XCD-aware bijective block swizzle (all grids used are %8==0)
  const int gx = gridDim.x, gy = gridDim.y;
  const int nwg = gx * gy;
  int wg = (int)blockIdx.y * gx + (int)blockIdx.x;
  if ((nwg & 7) == 0) wg = (wg & 7) * (nwg >> 3) + (wg >> 3);
  const int tn = wg % gx;
  const int tm = wg / gx;
  const int m0 = tm * 256, n0 = tn * 256;
  const int nT = KS >> 6;

  // staging source (pre-swizzled global granule)
  const int rowS = tid >> 3;
  const int gsw  = ((tid & 7) ^ (rowS & 7)) * 8;
  const unsigned short* a_src = A  + (size_t)(m0 + rowS) * lda + gsw;
  const unsigned short* b_src = Bt + (size_t)(n0 + rowS) * ldb + gsw;

  auto stageA_lo = [&](int t, int b) {
    const unsigned short* s = a_src + t*64;
    gld_lds16(s,                    &lds_a[b][    0 + wv*512]);
    gld_lds16(s + (size_t)64*lda,   &lds_a[b][ 4096 + wv*512]);
  };
  auto stageA_hi = [&](int t, int b) {
    const unsigned short* s = a_src + t*64 + (size_t)128*lda;
    gld_lds16(s,                    &lds_a[b][ 8192 + wv*512]);
    gld_lds16(s + (size_t)64*lda,   &lds_a[b][12288 + wv*512]);
  };
  auto stageB_lo = [&](int t, int b) {
    const unsigned short* s = b_src + t*64;
    gld_lds16(s,                    &lds_b[b][    0 + wv*512]);
    gld_lds16(s + (size_t)64*ldb,   &lds_b[b][ 4096 + wv*512]);
  };
  auto stageB_hi = [&](int t, int b) {
    const unsigned short* s = b_src + t*64 + (size_t)128*ldb;
    gld_lds16(s,                    &lds_b[b][ 8192 + wv*512]);
    gld_lds16(s + (size_t)64*ldb,   &lds_b[b][12288 + wv*512]);
  };

  // fragment read offsets (swizzled; r&7 == lane15&7 for all frag rows)
  const int soff0 = ((laneh)     ^ (lane15 & 7)) * 8;   // ks=0 granules 0..3
  const int soff1 = ((4 + laneh) ^ (lane15 & 7)) * 8;   // ks=1 granules 4..7
  const int arow = (wm*16 + lane15) * 64;
  const int brow = (wn*16 + lane15) * 64;

  floatx4 acc[8][4];
  #pragma unroll
  for (int i = 0; i < 8; i++)
    #pragma unroll
    for (int j = 0; j < 4; j++) acc[i][j] = (floatx4){0.f,0.f,0.f,0.f};

  bf16x8 af[4][2], bfr[2][2];

  // prologue: tile0 fully + AL(1), BH(1), AH(1); retire tile0, leave 6 loads.
  stageA_lo(0,0); stageB_lo(0,0); stageA_hi(0,0); stageB_hi(0,0);
  if (nT > 1) { stageA_lo(1,1); stageB_hi(1,1); stageA_hi(1,1); }
  wait_vm6();
  sbar();

  for (int t = 0; t < nT; ++t) {
    const int buf = t & 1;
    const unsigned short* la = &lds_a[buf][0];
    const unsigned short* lb = &lds_b[buf][0];

    // ---- P1: (A-lo, B-lo) ----
    #pragma unroll
    for (int ii = 0; ii < 4; ii++) {
      af[ii][0] = *(const bf16x8*)&la[arow + ii*2048 + soff0];
      af[ii][1] = *(const bf16x8*)&la[arow + ii*2048 + soff1];
    }
    #pragma unroll
    for (int jj = 0; jj < 2; jj++) {
      bfr[jj][0] = *(const bf16x8*)&lb[brow + jj*4096 + soff0];
      bfr[jj][1] = *(const bf16x8*)&lb[brow + jj*4096 + soff1];
    }
    if (t + 1 < nT) stageB_lo(t+1, buf^1);
    sbar();
    wait_lgkm0();
    __builtin_amdgcn_s_setprio(1);
    #pragma unroll
    for (int ks = 0; ks < 2; ks++)
      #pragma unroll
      for (int ii = 0; ii < 4; ii++)
        #pragma unroll
        for (int jj = 0; jj < 2; jj++)
          acc[ii][jj] = __builtin_amdgcn_mfma_f32_16x16x32_bf16(af[ii][ks], bfr[jj][ks], acc[ii][jj], 0, 0, 0);
    __builtin_amdgcn_s_setprio(0);
    sbar();

    // ---- P2: (A-lo, B-hi) — af reused ----
    #pragma unroll
    for (int jj = 0; jj < 2; jj++) {
      bfr[jj][0] = *(const bf16x8*)&lb[8192 + brow + jj*4096 + soff0];
      bfr[jj][1] = *(const bf16x8*)&lb[8192 + brow + jj*4096 + soff1];
    }
    if (t + 2 < nT) stageA_lo(t+2, buf);
    sbar();
    wait_lgkm0();
    __builtin_amdgcn_s_setprio(1);
    #pragma unroll
    for (int ks = 0; ks < 2; ks++)
      #pragma unroll
      for (int ii = 0; ii < 4; ii++)
        #pragma unroll
        for (int jj = 0; jj < 2; jj++)
          acc[ii][2+jj] = __builtin_amdgcn_mfma_f32_16x16x32_bf16(af[ii][ks], bfr[jj][ks], acc[ii][2+jj], 0, 0, 0);
    __builtin_amdgcn_s_setprio(0);
    sbar();

    // ---- P3: (A-hi, B-hi) — bfr reused ----
    #pragma unroll
    for (int ii = 0; ii < 4; ii++) {
      af[ii][0] = *(const bf16x8*)&la[8192 + arow + ii*2048 + soff0];
      af[ii][1] = *(const bf16x8*)&la[8192 + arow + ii*2048 + soff1];
    }
    if (t + 2 < nT) stageB_hi(t+2, buf);
    sbar();
    wait_lgkm0();
    __builtin_amdgcn_s_setprio(1);
    #pragma unroll
    for (int ks = 0; ks < 2; ks++)
      #pragma unroll
      for (int ii = 0; ii < 4; ii++)
        #pragma unroll
        for (int jj = 0; jj < 2; jj++)
          acc[4+ii][2+jj] = __builtin_amdgcn_mfma_f32_16x16x32_bf16(af[ii][ks], bfr[jj][ks], acc[4+ii][2+jj], 0, 0, 0);
    __builtin_amdgcn_s_setprio(0);
    sbar();

    // ---- P4: (A-hi, B-lo) — af reused, B-lo re-read ----
    #pragma unroll
    for (int jj = 0; jj < 2; jj++) {
      bfr[jj][0] = *(const bf16x8*)&lb[brow + jj*4096 + soff0];
      bfr[jj][1] = *(const bf16x8*)&lb[brow + jj*4096 + soff1];
    }
    if (t + 2 < nT) stageA_hi(t+2, buf);
    if (t < nT - 2) wait_vm6(); else wait_vm0();
    sbar();
    wait_lgkm0();
    __builtin_amdgcn_s_setprio(1);
    #pragma unroll
    for (int ks = 0; ks < 2; ks++)
      #pragma unroll
      for (int ii = 0; ii < 4; ii++)
        #pragma unroll
        for (int jj = 0; jj < 2; jj++)
          acc[4+ii][jj] = __builtin_amdgcn_mfma_f32_16x16x32_bf16(af[ii][ks], bfr[jj][ks], acc[4+ii][jj], 0, 0, 0);
    __builtin_amdgcn_s_setprio(0);
    sbar();
  }

  #pragma unroll
  for (int i = 0; i < 8; i++) {
    int row = m0 + (i>>2)*128 + (i&3)*32 + wm*16 + laneh*4;
    #pragma unroll
    for (int j = 0; j < 4; j++) {
      int col = n0 + (j>>1)*128 + (j&1)*64 + wn*16 + lane15;
      #pragma unroll
      for (int r = 0; r < 4; r++) {
        float v = acc[i][j][r];
        int rr = row + r;
        if constexpr (EPI == 0) {
          if (col < 2048) {
            outB[(size_t)rr*ldc + col] = f2bf(v);
          } else {
            int b = rr >> 10, t = rr & (Tq-1);
            int hd = col - 2048, hh = hd >> 6, d = hd & 63;
            vT[(((size_t)b*Hq + hh)*Dq + d)*Tq + t] = f2bf(v);
          }
        } else {
          float z = v + bias[col];
          float u = 0.79788456080286536f * (z + 0.044715f * z*z*z);
          float tt = 1.f - 2.f / (__expf(2.f*u) + 1.f);
          float gl = 0.5f * z * (1.f + tt);
          outB[(size_t)rr*ldc + col] = f2bf(gl);
        }
      }
    }
  }
}

// ---------------- split-K reduce: x += p0 + p1 + bias ----------------
__global__ __launch_bounds__(256) void splitk_reduce_kernel(
    const float* __restrict__ p, float* __restrict__ x,
    const float* __restrict__ bias)
{
  size_t o = ((size_t)blockIdx.x * 256 + threadIdx.x) * 4;
  float4 a = *(const float4*)(p + o);
  float4 b = *(const float4*)(p + (size_t)BT*Cq + o);
  float4 xv = *(const float4*)(x + o);
  float4 bi = *(const float4*)(bias + (o & (Cq-1)));
  xv.x += a.x + b.x + bi.x;
  xv.y += a.y + b.y + bi.y;
  xv.z += a.z + b.z + bi.z;
  xv.w += a.w + b.w + bi.w;
  *(float4*)(x + o) = xv;
}

// ---------------- flash attention (causal), S^T form (R6-verified) ----------------
__global__ __launch_bounds__(256)
void attn_kernel(const unsigned short* __restrict__ qk,   // (BT,2048): q 0..1023, k 1024..2047
                 const unsigned short* __restrict__ vT,   // (B,H,D,T)
                 unsigned short* __restrict__ ob)         // (BT,1024)
{
  __shared__ unsigned short Ks [2][64*64];
  __shared__ unsigned short Vts[2][64*64];
  __shared__ unsigned short Ps [4*16*64];
  int tid = threadIdx.x, lane = tid & 63, wv = tid >> 6;
  int lane15 = lane & 15, laneh = lane >> 4;
  int blk = blockIdx.x;
  int p = blk & 7, bh = blk >> 3;
  int h = bh & (Hq-1), b = bh >> 4;
  size_t tokbase = (size_t)b * Tq;
  const unsigned short* Kbase = qk + tokbase*2048 + 1024 + h*64;
  const unsigned short* Vbase = vT + (size_t)bh * Dq * Tq;

  int so  = (laneh ^ (lane15 & 7)) * 8;
  int so32 = so ^ 32;
  unsigned short* Pw = &Ps[wv*1024];

  auto stage = [&](int j0, int buf) {
    #pragma unroll
    for (int i = 0; i < 2; i++) {
      int seg = (wv*2+i)*64 + lane;
      int row = seg >> 3;
      int col = ((seg & 7) ^ (row & 7)) * 8;
      gld_lds16(Kbase + (size_t)(j0+row)*2048 + col, &Ks [buf][(wv*2+i)*512]);
      gld_lds16(Vbase + (size_t)row*Tq + j0 + col,   &Vts[buf][(wv*2+i)*512]);
    }
  };

  for (int phase = 0; phase < 2; ++phase) {
    int qt = phase ? (15 - p) : p;
    int qrow0 = qt*64 + wv*16;
    bf16x8 qf0, qf1;
    {
      const unsigned short* qp = qk + (tokbase + qrow0 + lane15)*2048 + h*64 + laneh*8;
      qf0 = *(const bf16x8*)(qp);
      qf1 = *(const bf16x8*)(qp + 32);
    }
    floatx4 oacc[4];
    #pragma unroll
    for (int d = 0; d < 4; d++) oacc[d] = (floatx4){0.f,0.f,0.f,0.f};
    float mrow = -__builtin_inff(), lrow = 0.f;
    int nT = qt + 1;

    __syncthreads();
    stage(0, 0);
    for (int it = 0; it < nT; ++it) {
      __syncthreads();
      if (it + 1 < nT) stage((it+1)*64, (it+1) & 1);
      int buf = it & 1;
      int j0 = it*64;

      floatx4 sac[4];
      #pragma unroll
      for (int jt = 0; jt < 4; jt++) {
        int row = jt*16 + lane15;
        bf16x8 kf0 = *(const bf16x8*)&Ks[buf][row*64 + so];
        bf16x8 kf1 = *(const bf16x8*)&Ks[buf][row*64 + so32];
        sac[jt] = (floatx4){0.f,0.f,0.f,0.f};
        sac[jt] = __builtin_amdgcn_mfma_f32_16x16x32_bf16(kf0, qf0, sac[jt], 0, 0, 0);
        sac[jt] = __builtin_amdgcn_mfma_f32_16x16x32_bf16(kf1, qf1, sac[jt], 0, 0, 0);
      }
      if (j0 + 63 > qrow0) {
        int tokg = qrow0 + lane15;
        #pragma unroll
        for (int jt = 0; jt < 4; jt++)
          #pragma unroll
          for (int r = 0; r < 4; r++) {
            int kv = j0 + jt*16 + laneh*4 + r;
            sac[jt][r] = (kv <= tokg) ? sac[jt][r] * 0.125f : -__builtin_inff();
          }
      } else {
        #pragma unroll
        for (int jt = 0; jt < 4; jt++)
          #pragma unroll
          for (int r = 0; r < 4; r++) sac[jt][r] *= 0.125f;
      }
      float mx = sac[0][0];
      #pragma unroll
      for (int jt = 0; jt < 4; jt++)
        #pragma unroll
        for (int r = 0; r < 4; r++) mx = fmaxf(mx, sac[jt][r]);
      mx = fmaxf(mx, __shfl_xor(mx, 16, 64));
      mx = fmaxf(mx, __shfl_xor(mx, 32, 64));
      float mn = fmaxf(mrow, mx);
      float alpha = __expf(mrow - mn);
      float psum = 0.f;
      #pragma unroll
      for (int jt = 0; jt < 4; jt++)
        #pragma unroll
        for (int r = 0; r < 4; r++) {
          float pv = __expf(sac[jt][r] - mn);
          sac[jt][r] = pv;
          psum += pv;
        }
      psum += __shfl_xor(psum, 16, 64);
      psum += __shfl_xor(psum, 32, 64);
      lrow = lrow * alpha + psum;
      mrow = mn;
      #pragma unroll
      for (int dt = 0; dt < 4; dt++)
        #pragma unroll
        for (int r = 0; r < 4; r++) oacc[dt][r] *= alpha;

      #pragma unroll
      for (int jt = 0; jt < 4; jt++) {
        unsigned int p0 = (unsigned int)f2bf(sac[jt][0]) | ((unsigned int)f2bf(sac[jt][1]) << 16);
        unsigned int p1 = (unsigned int)f2bf(sac[jt][2]) | ((unsigned int)f2bf(sac[jt][3]) << 16);
        int slot = (jt*2 + (laneh >> 1)) ^ (lane15 & 7);
        *(uint2*)&Pw[lane15*64 + slot*8 + (laneh & 1)*4] = make_uint2(p0, p1);
      }
      bf16x8 pf0 = *(const bf16x8*)&Pw[lane15*64 + so];
      bf16x8 pf1 = *(const bf16x8*)&Pw[lane15*64 + so32];
      #pragma unroll
      for (int dt = 0; dt < 4; dt++) {
        int row = dt*16 + lane15;
        bf16x8 vf0 = *(const bf16x8*)&Vts[buf][row*64 + so];
        bf16x8 vf1 = *(const bf16x8*)&Vts[buf][row*64 + so32];
        oacc[dt] = __builtin_amdgcn_mfma_f32_16x16x32_bf16(vf0, pf0, oacc[dt], 0, 0, 0);
        oacc[dt] = __builtin_amdgcn_mfma_f32_16x16x32_bf16(vf1, pf1, oacc[dt], 0, 0, 0);
      }
    }
    float inv = 1.f / lrow;
    unsigned short* orow = ob + (tokbase + qrow0 + lane15)*Cq + h*64 + laneh*4;
    #pragma unroll
    for (int dt = 0; dt < 4; dt++) {
      unsigned int u0 = (unsigned int)f2bf(oacc[dt][0]*inv) | ((unsigned int)f2bf(oacc[dt][1]*inv) << 16);
      unsigned int u1 = (unsigned int)f2bf(oacc[dt][2]*inv) | ((unsigned int)f2bf(oacc[dt][3]*inv) << 16);
      *(uint2*)&orow[dt*16] = make_uint2(u0, u1);
    }
  }
}

// ---------------- lm head prep ----------------
__global__ __launch_bounds__(256) void lmw_prep_kernel(
    const float* __restrict__ lmW, unsigned short* __restrict__ lmWt,
    float* __restrict__ lmWcol)
{
  int idx = blockIdx.x * 256 + threadIdx.x;
  int n = idx & 63, k = idx >> 6;
  lmWt[(size_t)n*Cq + k] = f2bf(lmW[(size_t)k*65 + n]);
  if (idx < Cq) lmWcol[idx] = lmW[(size_t)idx*65 + 64];
}

// ---------------- head: MFMA logits + fused log-softmax + log-sigmoid(dur) ----------------
__global__ __launch_bounds__(64) void head_mfma_kernel(
    const float* __restrict__ x, const unsigned short* __restrict__ lmWt,
    const float* __restrict__ lmWcol, const float* __restrict__ lmb,
    float* __restrict__ out)
{
  int lane = threadIdx.x;
  int lane15 = lane & 15, laneh = lane >> 4;
  int tok0 = blockIdx.x * 16;

  floatx4 acc[4];
  #pragma unroll
  for (int jt = 0; jt < 4; jt++) acc[jt] = (floatx4){0.f,0.f,0.f,0.f};

  const float* xrow = x + (size_t)(tok0 + lane15) * Cq + laneh*8;
  const unsigned short* brow = lmWt + (size_t)lane15 * Cq + laneh*8;

  for (int k0 = 0; k0 < Cq; k0 += 32) {
    float4 a0 = *(const float4*)(xrow + k0);
    float4 a1 = *(const float4*)(xrow + k0 + 4);
    bf16x8 af;
    af[0] = (__bf16)a0.x; af[1] = (__bf16)a0.y; af[2] = (__bf16)a0.z; af[3] = (__bf16)a0.w;
    af[4] = (__bf16)a1.x; af[5] = (__bf16)a1.y; af[6] = (__bf16)a1.z; af[7] = (__bf16)a1.w;
    #pragma unroll
    for (int jt = 0; jt < 4; jt++) {
      bf16x8 bfv = *(const bf16x8*)(brow + (size_t)jt*16*Cq + k0);
      acc[jt] = __builtin_amdgcn_mfma_f32_16x16x32_bf16(af, bfv, acc[jt], 0, 0, 0);
    }
  }
  #pragma unroll
  for (int jt = 0; jt < 4; jt++) {
    float bias = lmb[jt*16 + lane15];
    #pragma unroll
    for (int r = 0; r < 4; r++) acc[jt][r] += bias;
  }
  #pragma unroll
  for (int r = 0; r < 4; r++) {
    float m = fmaxf(fmaxf(acc[0][r], acc[1][r]), fmaxf(acc[2][r], acc[3][r]));
    #pragma unroll
    for (int s = 1; s < 16; s <<= 1) m = fmaxf(m, __shfl_xor(m, s, 64));
    float se = 0.f;
    #pragma unroll
    for (int jt = 0; jt < 4; jt++) se += expf(acc[jt][r] - m);
    #pragma unroll
    for (int s = 1; s < 16; s <<= 1) se += __shfl_xor(se, s, 64);
    float lse = m + logf(se);
    int tok = tok0 + laneh*4 + r;
    float* orow = out + (size_t)tok * 65;
    #pragma unroll
    for (int jt = 0; jt < 4; jt++)
      orow[jt*16 + lane15] = acc[jt][r] - lse;
  }
  int t = lane >> 2, kq = (lane & 3) * 256;
  const float* xr2 = x + (size_t)(tok0 + t) * Cq + kq;
  const float* wc = lmWcol + kq;
  float s = 0.f;
  #pragma unroll 4
  for (int i = 0; i < 256; i += 4) {
    float4 xv = *(const float4*)(xr2 + i);
    float4 wv = *(const float4*)(wc + i);
    s += xv.x*wv.x + xv.y*wv.y + xv.z*wv.z + xv.w*wv.w;
  }
  s += __shfl_xor(s, 1, 64);
  s += __shfl_xor(s, 2, 64);
  if ((lane & 3) == 0) {
    float z = s + lmb[64];
    float ls = (z >= 0.f) ? -log1pf(expf(-z)) : (z - log1pf(expf(z)));
    out[(size_t)(tok0 + t) * 65 + 64] = ls;
  }
}

extern "C" void kernel_launch(void* const* d_in, const int* in_sizes, int n_in,
                              void* d_out, int out_size, void* d_ws, size_t ws_size,
                              hipStream_t stream) {
  const int*   acts = (const int*)  d_in[0];
  const float* dur  = (const float*)d_in[1];
  const float* emb  = (const float*)d_in[2];
  const float* pos  = (const float*)d_in[3];
  const float* Wq   = (const float*)d_in[4];
  const float* Wk   = (const float*)d_in[5];
  const float* Wv   = (const float*)d_in[6];
  const float* Wo   = (const float*)d_in[7];
  const float* bo   = (const float*)d_in[8];
  const float* W1   = (const float*)d_in[9];
  const float* b1   = (const float*)d_in[10];
  const float* W2   = (const float*)d_in[11];
  const float* b2   = (const float*)d_in[12];
  const float* g1   = (const float*)d_in[13];
  const float* g2   = (const float*)d_in[14];
  const float* lmW  = (const float*)d_in[15];
  const float* lmb  = (const float*)d_in[16];
  float* out = (float*)d_out;
  (void)in_sizes; (void)n_in; (void)out_size; (void)ws_size;

  char* w = (char*)d_ws;
  auto take = [&](size_t bytes) { char* p = w; w += (bytes + 255) & ~(size_t)255; return p; };
  unsigned short* qk  = (unsigned short*)take((size_t)BT*2048*2);
  unsigned short* vT  = (unsigned short*)take((size_t)Bq*Hq*Dq*Tq*2);
  unsigned short* ob  = (unsigned short*)take((size_t)BT*Cq*2);
  unsigned short* m1  = qk;                      // FF1 out aliases qk+vT+ob (32 MB)
  unsigned short* hb  = (unsigned short*)take((size_t)BT*Cq*2);
  float*          x   = (float*)take((size_t)BT*Cq*4);
  unsigned short* wqkvl = (unsigned short*)take((size_t)3072*Cq*2);
  unsigned short* wol   = (unsigned short*)take((size_t)Cq*Cq*2);
  unsigned short* w1l   = (unsigned short*)take((size_t)Fq*Cq*2);
  unsigned short* w2l   = (unsigned short*)take((size_t)Cq*Fq*2);
  unsigned short* lmWt  = (unsigned short*)take((size_t)64*Cq*2);
  float*          lmWcol= (float*)take((size_t)Cq*4);
  float*          part  = (float*)take((size_t)2*BT*Cq*4);   // split-K partials (32 MB)

  dim3 tb(32, 8);
  embed_kernel<<<BT, 256, 0, stream>>>(acts, dur, emb, pos, x);
  lmw_prep_kernel<<<256, 256, 0, stream>>>(lmW, lmWt, lmWcol);

  for (int l = 0; l < Lq; l++) {
    prep_layer_kernel<<<12288, tb, 0, stream>>>(
        Wq + (size_t)l*Hq*Cq*Dq, Wk + (size_t)l*Hq*Cq*Dq, Wv + (size_t)l*Hq*Cq*Dq,
        Wo + (size_t)l*Cq*Cq, W1 + (size_t)l*Cq*Fq, W2 + (size_t)l*Fq*Cq,
        wqkvl, wol, w1l, w2l);

    rmsnorm_kernel<<<BT, 256, 0, stream>>>(x, g1 + l*Cq, hb);
    gemm256_kernel<0><<<dim3(12,16), 512, 0, stream>>>(
        hb, Cq, wqkvl, Cq, Cq, qk, 2048, vT, nullptr);
    attn_kernel<<<Bq*Hq*8, 256, 0, stream>>>(qk, vT, ob);
    gemm_bt_kernel<2><<<dim3(8,32), 256, 0, stream>>>(
        ob, Cq, wol, Cq, Cq, nullptr, 0, nullptr, x, Cq, bo + l*Cq);
    rmsnorm_kernel<<<BT, 256, 0, stream>>>(x, g2 + l*Cq, hb);
    gemm256_kernel<1><<<dim3(16,16), 512, 0, stream>>>(
        hb, Cq, w1l, Cq, Cq, m1, Fq, nullptr, b1 + l*Fq);
    gemm_bt_kernel<3><<<dim3(8,32,2), 256, 0, stream>>>(
        m1, Fq, w2l, Fq, 2048, nullptr, 0, nullptr, part, Cq, nullptr);
    splitk_reduce_kernel<<<BT*Cq/1024, 256, 0, stream>>>(part, x, b2 + l*Cq);
  }
  head_mfma_kernel<<<BT/16, 64, 0, stream>>>(x, lmWt, lmWcol, lmb, out);
}

// Round 5
// 1246.124 us; speedup vs baseline: 1.0074x; 1.0047x over previous
//
#include <hip/hip_runtime.h>

// Problem constants
#define Bq 4
#define Tq 1024
#define Cq 1024
#define Hq 16
#define Dq 64
#define Fq 4096
#define Lq 4
#define BT (Bq*Tq)

typedef __attribute__((ext_vector_type(8))) __bf16 bf16x8;
typedef __attribute__((ext_vector_type(4))) float  floatx4;

__device__ __forceinline__ unsigned short f2bf(float f) {
  unsigned int u = __builtin_bit_cast(unsigned int, f);
  u = (u + 0x7FFFu + ((u >> 16) & 1u)) >> 16;   // RNE
  return (unsigned short)u;
}

// async global->LDS, 16B per lane; lds ptr must be wave-uniform (HW adds lane*16)
__device__ __forceinline__ void gld_lds16(const void* g, void* lds) {
  __builtin_amdgcn_global_load_lds(
      (const __attribute__((address_space(1))) unsigned int*)g,
      (__attribute__((address_space(3))) unsigned int*)lds, 16, 0, 0);
}

// partial-drain barrier used by the legacy 128^2 kernel (measured-good)
__device__ __forceinline__ void barrier_vmcnt4() {
  asm volatile("s_waitcnt vmcnt(4)\n\ts_barrier" ::: "memory");
}

// full LDS-sync barrier for the 256^2 kernel: drain this wave's LDS ops,
// then barrier. "memory" clobber gives IR-level ordering (typed ds stores
// cannot sink past / loads cannot hoist above); r2==r3 showed the clobber
// costs nothing. sched_barrier(0) pins the machine scheduler (rule #18).
__device__ __forceinline__ void tbar_lds() {
  __builtin_amdgcn_sched_barrier(0);
  asm volatile("s_waitcnt lgkmcnt(0)\n\ts_barrier" ::: "memory");
  __builtin_amdgcn_sched_barrier(0);
}

// ---------------- embed: x = concat(emb[acts], dur) + pos ----------------
__global__ __launch_bounds__(256) void embed_kernel(
    const int* __restrict__ acts, const float* __restrict__ dur,
    const float* __restrict__ emb, const float* __restrict__ pos,
    float* __restrict__ x)
{
  int tok = blockIdx.x;
  int t = tok & (Tq-1);
  int a = acts[tok];
  const float* er = emb + (size_t)a * (Cq-1);
  const float* pr = pos + (size_t)t * Cq;
  float* xr = x + (size_t)tok * Cq;
  float dv = dur[tok];
  for (int c = threadIdx.x; c < Cq; c += 256) {
    float v = (c < Cq-1) ? er[c] : dv;
    xr[c] = v + pr[c];
  }
}

// ---------------- rmsnorm -> bf16 ----------------
__global__ __launch_bounds__(256) void rmsnorm_kernel(
    const float* __restrict__ x, const float* __restrict__ g,
    unsigned short* __restrict__ h)
{
  int tok = blockIdx.x, tid = threadIdx.x;
  const float4* xr = (const float4*)(x + (size_t)tok * Cq);
  float4 v = xr[tid];
  float ss = v.x*v.x + v.y*v.y + v.z*v.z + v.w*v.w;
  #pragma unroll
  for (int s = 32; s >= 1; s >>= 1) ss += __shfl_xor(ss, s, 64);
  __shared__ float ws4[4];
  if ((tid & 63) == 0) ws4[tid >> 6] = ss;
  __syncthreads();
  float tot = ws4[0] + ws4[1] + ws4[2] + ws4[3];
  float r = rsqrtf(tot * (1.0f/(float)Cq) + 1.1920928955078125e-07f);
  float4 gv = ((const float4*)g)[tid];
  unsigned short o4[4] = { f2bf(v.x*r*gv.x), f2bf(v.y*r*gv.y),
                           f2bf(v.z*r*gv.z), f2bf(v.w*r*gv.w) };
  *(uint2*)(h + (size_t)tok*Cq + tid*4) = *(const uint2*)o4;
}

// ---------------- fused per-layer weight prep: all 6 transposes in 1 launch ----------------
__global__ void prep_layer_kernel(
    const float* __restrict__ Wq, const float* __restrict__ Wk,
    const float* __restrict__ Wv, const float* __restrict__ Wo,
    const float* __restrict__ W1, const float* __restrict__ W2,
    unsigned short* __restrict__ wqkvl, unsigned short* __restrict__ wol,
    unsigned short* __restrict__ w1l,   unsigned short* __restrict__ w2l)
{
  __shared__ float tile[32][33];
  int z = blockIdx.x;
  const float* in; unsigned short* out;
  int R, Cc, tx, ty;
  if (z < 3072) {
    int i = z >> 10, t = z & 1023;
    int hh = t >> 6, rem = t & 63;
    ty = rem >> 1; tx = rem & 1;
    const float* w = (i == 0) ? Wq : (i == 1) ? Wk : Wv;
    in = w + (size_t)hh * Cq * Dq;
    out = wqkvl + (size_t)i * 1024 * 1024 + (size_t)hh * 64 * 1024;
    R = 1024; Cc = 64;
  } else if (z < 4096) {
    int t = z - 3072;
    tx = t & 31; ty = t >> 5;
    in = Wo; out = wol; R = 1024; Cc = 1024;
  } else if (z < 8192) {
    int t = z - 4096;
    tx = t & 127; ty = t >> 7;
    in = W1; out = w1l; R = 1024; Cc = 4096;
  } else {
    int t = z - 8192;
    tx = t & 31; ty = t >> 5;
    in = W2; out = w2l; R = 4096; Cc = 1024;
  }
  int c0 = tx * 32, r0 = ty * 32;
  int lx = threadIdx.x, ly = threadIdx.y;  // 32 x 8
  #pragma unroll
  for (int i = 0; i < 32; i += 8)
    tile[ly+i][lx] = in[(size_t)(r0+ly+i)*Cc + c0 + lx];
  __syncthreads();
  #pragma unroll
  for (int i = 0; i < 32; i += 8)
    out[(size_t)(c0+ly+i)*R + r0 + lx] = f2bf(tile[lx][ly+i]);
}

// ---------------- legacy 128^2 GEMM + XCD-aware block swizzle ----------------
// QKV: EPI 0, Wo: EPI 2, FF2: EPI 3. All grids used are %8==0 so the simple
// bijective remap applies: XCD k (orig%8==k) gets a contiguous chunk of work
// ids -> neighboring tiles (shared A-panel) land in the same XCD L2 (T1).
template <int EPI>
__global__ __launch_bounds__(256)
void gemm_bt_kernel(const unsigned short* __restrict__ A, int lda,
                    const unsigned short* __restrict__ Bt, int ldb,
                    int KS,
                    unsigned short* __restrict__ outB, int ldc,
                    unsigned short* __restrict__ vT,
                    float* __restrict__ outF, int ldf,
                    const float* __restrict__ bias)
{
  __shared__ unsigned short lds_a[3*4096];
  __shared__ unsigned short lds_b[3*4096];
  int tid = threadIdx.x;
  int lane = tid & 63, wv = tid >> 6;
  int lane15 = lane & 15, laneh = lane >> 4;

  const int gx = gridDim.x, gy = gridDim.y;
  const int nwg = gx * gy * (int)gridDim.z;
  int wg = ((int)blockIdx.z * gy + (int)blockIdx.y) * gx + (int)blockIdx.x;
  if ((nwg & 7) == 0) wg = (wg & 7) * (nwg >> 3) + (wg >> 3);
  const int tn = wg % gx;
  int rem = wg / gx;
  const int tm = rem % gy;
  const int tz = rem / gy;

  int m0 = tm * 128, n0 = tn * 128;
  int wm = wv & 1, wn = wv >> 1;

  floatx4 acc[4][4];
  #pragma unroll
  for (int i = 0; i < 4; i++)
    #pragma unroll
    for (int j = 0; j < 4; j++) acc[i][j] = (floatx4){0.f,0.f,0.f,0.f};

  int seg0 = (wv*2+0)*64 + lane;
  int seg1 = (wv*2+1)*64 + lane;
  int ra0 = seg0 >> 2, ca0 = ((seg0 & 3) ^ (ra0 & 3)) * 8;
  int ra1 = seg1 >> 2, ca1 = ((seg1 & 3) ^ (ra1 & 3)) * 8;
  const unsigned short* a_src0 = A  + (size_t)(m0+ra0)*lda + ca0;
  const unsigned short* a_src1 = A  + (size_t)(m0+ra1)*lda + ca1;
  const unsigned short* b_src0 = Bt + (size_t)(n0+ra0)*ldb + ca0;
  const unsigned short* b_src1 = Bt + (size_t)(n0+ra1)*ldb + ca1;
  unsigned short* a_dst0 = &lds_a[(wv*2+0)*512];
  unsigned short* a_dst1 = &lds_a[(wv*2+1)*512];
  unsigned short* b_dst0 = &lds_b[(wv*2+0)*512];
  unsigned short* b_dst1 = &lds_b[(wv*2+1)*512];

  int sx = (laneh ^ (lane15 & 3)) * 8;

  int kbeg = (EPI == 3) ? tz * KS : 0;
  int nIter = KS >> 5;

  auto stage = [&](int k0, int buf) {
    int off = buf * 4096;
    gld_lds16(a_src0 + k0, a_dst0 + off);
    gld_lds16(a_src1 + k0, a_dst1 + off);
    gld_lds16(b_src0 + k0, b_dst0 + off);
    gld_lds16(b_src1 + k0, b_dst1 + off);
  };

  stage(kbeg, 0);
  stage(kbeg + 32, 1);
  int cb = 0, pb = 2;
  for (int it = 0; it < nIter; ++it) {
    barrier_vmcnt4();
    if (it + 2 < nIter) stage(kbeg + (it+2)*32, pb);
    const unsigned short* la = &lds_a[cb*4096];
    const unsigned short* lb = &lds_b[cb*4096];
    bf16x8 af[4], bf[4];
    #pragma unroll
    for (int i = 0; i < 4; i++)
      af[i] = *(const bf16x8*)&la[(wm*64 + i*16 + lane15)*32 + sx];
    #pragma unroll
    for (int j = 0; j < 4; j++)
      bf[j] = *(const bf16x8*)&lb[(wn*64 + j*16 + lane15)*32 + sx];
    #pragma unroll
    for (int i = 0; i < 4; i++)
      #pragma unroll
      for (int j = 0; j < 4; j++)
        acc[i][j] = __builtin_amdgcn_mfma_f32_16x16x32_bf16(af[i], bf[j], acc[i][j], 0, 0, 0);
    cb = (cb == 2) ? 0 : cb + 1;
    pb = (pb == 2) ? 0 : pb + 1;
  }

  float* outFz = (EPI == 3) ? outF + (size_t)tz * BT * Cq : outF;

  #pragma unroll
  for (int i = 0; i < 4; i++) {
    int row = m0 + wm*64 + i*16 + laneh*4;
    #pragma unroll
    for (int j = 0; j < 4; j++) {
      int col = n0 + wn*64 + j*16 + lane15;
      #pragma unroll
      for (int r = 0; r < 4; r++) {
        float v = acc[i][j][r];
        int rr = row + r;
        if constexpr (EPI == 0) {
          if (col < 2048) {
            outB[(size_t)rr*ldc + col] = f2bf(v);
          } else {
            int b = rr >> 10, t = rr & (Tq-1);
            int hd = col - 2048, hh = hd >> 6, d = hd & 63;
            vT[(((size_t)b*Hq + hh)*Dq + d)*Tq + t] = f2bf(v);
          }
        } else if constexpr (EPI == 1) {
          float z = v + bias[col];
          float u = 0.79788456080286536f * (z + 0.044715f * z*z*z);
          float t = 1.f - 2.f / (__expf(2.f*u) + 1.f);
          float gl = 0.5f * z * (1.f + t);
          outB[(size_t)rr*ldc + col] = f2bf(gl);
        } else if constexpr (EPI == 2) {
          outF[(size_t)rr*ldf + col] += v + bias[col];
        } else {
          outFz[(size_t)rr*ldf + col] = v;
        }
      }
    }
  }
}

// ---------------- 256^2 4-phase GEMM, reg-staged, v3 (SHADOW this round) ----
// Staging global->VGPR->ds_write (bf16x8-typed on BOTH sides: no mixed-type
// LDS aliasing). ONE full-LDS-sync barrier per phase (tbar_lds: this wave's
// lgkm drained BEFORE barrier-arrive => at each barrier every wave's phase-P
// reads AND writes are retired). Region ledger (all >=1 barrier separation):
//   P1 writes B-lo[buf^1] (last read P4 of t-1) ; reads A-lo,B-lo[buf]
//   P2 writes A-lo[buf]   (last read P1 of t)   ; reads B-hi[buf]
//   P3 writes B-hi[buf]   (last read P2 of t)   ; reads A-hi[buf]
//   P4 writes A-hi[buf]   (last read P3 of t)   ; reads B-lo[buf]
// Loads issued 2 phases before their ds_write (X: P1->P3->P1, Y: P2->P4->P2)
// so compiler-inserted precise vmcnt covers ~2 phases of latency (T14).
// Swizzle on the write side: LDS granule g^(r&7) of row r holds global
// granule g — image identical to the refcheck-verified DMA version.
__global__ __launch_bounds__(512, 2)
void gemm256r_kernel(const unsigned short* __restrict__ A, int lda,
                     const unsigned short* __restrict__ Bt, int ldb,
                     int KS,
                     unsigned short* __restrict__ outB, int ldc,
                     const float* __restrict__ bias)
{
  __shared__ unsigned short lds_a[2][256*64];
  __shared__ unsigned short lds_b[2][256*64];
  const int tid = threadIdx.x;
  const int lane = tid & 63, wv = tid >> 6;
  const int lane15 = lane & 15, laneh = lane >> 4;
  const int wm = wv & 1, wn = wv >> 1;      // 2 x 4 waves

  const int gx = gridDim.x, gy = gridDim.y;
  const int nwg = gx * gy;
  int wg = (int)blockIdx.y * gx + (int)blockIdx.x;
  if ((nwg & 7) == 0) wg = (wg & 7) * (nwg >> 3) + (wg >> 3);
  const int tn = wg % gx;
  const int tm = wg / gx;
  const int m0 = tm * 256, n0 = tn * 256;
  const int nT = KS >> 6;

  const int rowS = tid >> 3;
  const int gS  = tid & 7;
  const int swz = (gS ^ (rowS & 7)) * 8;    // write-side XOR swizzle

  auto ldA = [&](int kt, int h, bf16x8& r0, bf16x8& r1) {
    const unsigned short* s = A + (size_t)(m0 + h*128 + rowS)*lda + kt*64 + gS*8;
    r0 = *(const bf16x8*)s;
    r1 = *(const bf16x8*)(s + (size_t)64*lda);
  };
  auto ldB = [&](int kt, int h, bf16x8& r0, bf16x8& r1) {
    const unsigned short* s = Bt + (size_t)(n0 + h*128 + rowS)*ldb + kt*64 + gS*8;
    r0 = *(const bf16x8*)s;
    r1 = *(const bf16x8*)(s + (size_t)64*ldb);
  };
  auto wrA = [&](int h, int b, bf16x8 r0, bf16x8 r1) {
    unsigned short* d = &lds_a[b][(h*128 + rowS)*64 + swz];
    *(bf16x8*)d = r0;
    *(bf16x8*)(d + 64*64) = r1;
  };
  auto wrB = [&](int h, int b, bf16x8 r0, bf16x8 r1) {
    unsigned short* d = &lds_b[b][(h*128 + rowS)*64 + swz];
    *(bf16x8*)d = r0;
    *(bf16x8*)(d + 64*64) = r1;
  };

  const int soff0 = ((laneh)     ^ (lane15 & 7)) * 8;   // ks=0 granules 0..3
  const int soff1 = ((4 + laneh) ^ (lane15 & 7)) * 8;   // ks=1 granules 4..7
  const int arow = (wm*16 + lane15) * 64;
  const int brow = (wn*16 + lane15) * 64;

  floatx4 acc[8][4];
  #pragma unroll
  for (int i = 0; i < 8; i++)
    #pragma unroll
    for (int j = 0; j < 4; j++) acc[i][j] = (floatx4){0.f,0.f,0.f,0.f};

  bf16x8 af[4][2], bfr[2][2];
  bf16x8 sX0, sX1, sY0, sY1;

  // prologue: stage tile0 fully; prime X=B-lo(1), Y=A-lo(2)
  ldA(0, 0, sX0, sX1); ldB(0, 0, sY0, sY1);
  wrA(0, 0, sX0, sX1); wrB(0, 0, sY0, sY1);
  ldA(0, 1, sX0, sX1); ldB(0, 1, sY0, sY1);
  wrA(1, 0, sX0, sX1); wrB(1, 0, sY0, sY1);
  if (nT > 1) ldB(1, 0, sX0, sX1);
  if (nT > 2) ldA(2, 0, sY0, sY1);
  tbar_lds();

  for (int t = 0; t < nT; ++t) {
    const int buf = t & 1;
    const unsigned short* la = &lds_a[buf][0];
    const unsigned short* lb = &lds_b[buf][0];

    // ---- P1: (A-lo, B-lo) ----
    #pragma unroll
    for (int ii = 0; ii < 4; ii++) {
      af[ii][0] = *(const bf16x8*)&la[arow + ii*2048 + soff0];
      af[ii][1] = *(const bf16x8*)&la[arow + ii*2048 + soff1];
    }
    #pragma unroll
    for (int jj = 0; jj < 2; jj++) {
      bfr[jj][0] = *(const bf16x8*)&lb[brow + jj*4096 + soff0];
      bfr[jj][1] = *(const bf16x8*)&lb[brow + jj*4096 + soff1];
    }
    if (t + 1 < nT) wrB(0, buf^1, sX0, sX1);   // B-lo(t+1), loaded P3 of t-1
    if (t + 2 < nT) ldB(t+2, 1, sX0, sX1);     // B-hi(t+2) -> X
    __builtin_amdgcn_s_setprio(1);
    #pragma unroll
    for (int ks = 0; ks < 2; ks++)
      #pragma unroll
      for (int ii = 0; ii < 4; ii++)
        #pragma unroll
        for (int jj = 0; jj < 2; jj++)
          acc[ii][jj] = __builtin_amdgcn_mfma_f32_16x16x32_bf16(af[ii][ks], bfr[jj][ks], acc[ii][jj], 0, 0, 0);
    __builtin_amdgcn_s_setprio(0);
    tbar_lds();

    // ---- P2: (A-lo, B-hi) — af reused ----
    #pragma unroll
    for (int jj = 0; jj < 2; jj++) {
      bfr[jj][0] = *(const bf16x8*)&lb[8192 + brow + jj*4096 + soff0];
      bfr[jj][1] = *(const bf16x8*)&lb[8192 + brow + jj*4096 + soff1];
    }
    if (t + 2 < nT) wrA(0, buf, sY0, sY1);     // A-lo(t+2), loaded P4 of t-1
    if (t + 2 < nT) ldA(t+2, 1, sY0, sY1);     // A-hi(t+2) -> Y
    __builtin_amdgcn_s_setprio(1);
    #pragma unroll
    for (int ks = 0; ks < 2; ks++)
      #pragma unroll
      for (int ii = 0; ii < 4; ii++)
        #pragma unroll
        for (int jj = 0; jj < 2; jj++)
          acc[ii][2+jj] = __builtin_amdgcn_mfma_f32_16x16x32_bf16(af[ii][ks], bfr[jj][ks], acc[ii][2+jj], 0, 0, 0);
    __builtin_amdgcn_s_setprio(0);
    tbar_lds();

    // ---- P3: (A-hi, B-hi) — bfr reused ----
    #pragma unroll
    for (int ii = 0; ii < 4; ii++) {
      af[ii][0] = *(const bf16x8*)&la[8192 + arow + ii*2048 + soff0];
      af[ii][1] = *(const bf16x8*)&la[8192 + arow + ii*2048 + soff1];
    }
    if (t + 2 < nT) wrB(1, buf, sX0, sX1);     // B-hi(t+2), loaded P1 of t
    if (t + 2 < nT) ldB(t+2, 0, sX0, sX1);     // B-lo(t+2) -> X
    __builtin_amdgcn_s_setprio(1);
    #pragma unroll
    for (int ks = 0; ks < 2; ks++)
      #pragma unroll
      for (int ii = 0; ii < 4; ii++)
        #pragma unroll
        for (int jj = 0; jj < 2; jj++)
          acc[4+ii][2+jj] = __builtin_amdgcn_mfma_f32_16x16x32_bf16(af[ii][ks], bfr[jj][ks], acc[4+ii][2+jj], 0, 0, 0);
    __builtin_amdgcn_s_setprio(0);
    tbar_lds();

    // ---- P4: (A-hi, B-lo) — af reused, B-lo re-read ----
    #pragma unroll
    for (int jj = 0; jj < 2; jj++) {
      bfr[jj][0] = *(const bf16x8*)&lb[brow + jj*4096 + soff0];
      bfr[jj][1] = *(const bf16x8*)&lb[brow + jj*4096 + soff1];
    }
    if (t + 2 < nT) wrA(1, buf, sY0, sY1);     // A-hi(t+2), loaded P2 of t
    if (t + 3 < nT) ldA(t+3, 0, sY0, sY1);     // A-lo(t+3) -> Y
    __builtin_amdgcn_s_setprio(1);
    #pragma unroll
    for (int ks = 0; ks < 2; ks++)
      #pragma unroll
      for (int ii = 0; ii < 4; ii++)
        #pragma unroll
        for (int jj = 0; jj < 2; jj++)
          acc[4+ii][jj] = __builtin_amdgcn_mfma_f32_16x16x32_bf16(af[ii][ks], bfr[jj][ks], acc[4+ii][jj], 0, 0, 0);
    __builtin_amdgcn_s_setprio(0);
    tbar_lds();
  }

  #pragma unroll
  for (int i = 0; i < 8; i++) {
    int row = m0 + (i>>2)*128 + (i&3)*32 + wm*16 + laneh*4;
    #pragma unroll
    for (int j = 0; j < 4; j++) {
      int col = n0 + (j>>1)*128 + (j&1)*64 + wn*16 + lane15;
      #pragma unroll
      for (int r = 0; r < 4; r++) {
        float v = acc[i][j][r];
        int rr = row + r;
        float z = v + bias[col];
        float u = 0.79788456080286536f * (z + 0.044715f * z*z*z);
        float tt = 1.f - 2.f / (__expf(2.f*u) + 1.f);
        float gl = 0.5f * z * (1.f + tt);
        outB[(size_t)rr*ldc + col] = f2bf(gl);
      }
    }
  }
}

// ---------------- split-K reduce: x += p0 + p1 + bias ----------------
__global__ __launch_bounds__(256) void splitk_reduce_kernel(
    const float* __restrict__ p, float* __restrict__ x,
    const float* __restrict__ bias)
{
  size_t o = ((size_t)blockIdx.x * 256 + threadIdx.x) * 4;
  float4 a = *(const float4*)(p + o);
  float4 b = *(const float4*)(p + (size_t)BT*Cq + o);
  float4 xv = *(const float4*)(x + o);
  float4 bi = *(const float4*)(bias + (o & (Cq-1)));
  xv.x += a.x + b.x + bi.x;
  xv.y += a.y + b.y + bi.y;
  xv.z += a.z + b.z + bi.z;
  xv.w += a.w + b.w + bi.w;
  *(float4*)(x + o) = xv;
}

// ---------------- flash attention (causal), S^T form (R6-verified) ----------------
__global__ __launch_bounds__(256)
void attn_kernel(const unsigned short* __restrict__ qk,   // (BT,2048): q 0..1023, k 1024..2047
                 const unsigned short* __restrict__ vT,   // (B,H,D,T)
                 unsigned short* __restrict__ ob)         // (BT,1024)
{
  __shared__ unsigned short Ks [2][64*64];
  __shared__ unsigned short Vts[2][64*64];
  __shared__ unsigned short Ps [4*16*64];
  int tid = threadIdx.x, lane = tid & 63, wv = tid >> 6;
  int lane15 = lane & 15, laneh = lane >> 4;
  int blk = blockIdx.x;
  int p = blk & 7, bh = blk >> 3;
  int h = bh & (Hq-1), b = bh >> 4;
  size_t tokbase = (size_t)b * Tq;
  const unsigned short* Kbase = qk + tokbase*2048 + 1024 + h*64;
  const unsigned short* Vbase = vT + (size_t)bh * Dq * Tq;

  int so  = (laneh ^ (lane15 & 7)) * 8;
  int so32 = so ^ 32;
  unsigned short* Pw = &Ps[wv*1024];

  auto stage = [&](int j0, int buf) {
    #pragma unroll
    for (int i = 0; i < 2; i++) {
      int seg = (wv*2+i)*64 + lane;
      int row = seg >> 3;
      int col = ((seg & 7) ^ (row & 7)) * 8;
      gld_lds16(Kbase + (size_t)(j0+row)*2048 + col, &Ks [buf][(wv*2+i)*512]);
      gld_lds16(Vbase + (size_t)row*Tq + j0 + col,   &Vts[buf][(wv*2+i)*512]);
    }
  };

  for (int phase = 0; phase < 2; ++phase) {
    int qt = phase ? (15 - p) : p;
    int qrow0 = qt*64 + wv*16;
    bf16x8 qf0, qf1;
    {
      const unsigned short* qp = qk + (tokbase + qrow0 + lane15)*2048 + h*64 + laneh*8;
      qf0 = *(const bf16x8*)(qp);
      qf1 = *(const bf16x8*)(qp + 32);
    }
    floatx4 oacc[4];
    #pragma unroll
    for (int d = 0; d < 4; d++) oacc[d] = (floatx4){0.f,0.f,0.f,0.f};
    float mrow = -__builtin_inff(), lrow = 0.f;
    int nT = qt + 1;

    __syncthreads();
    stage(0, 0);
    for (int it = 0; it < nT; ++it) {
      __syncthreads();
      if (it + 1 < nT) stage((it+1)*64, (it+1) & 1);
      int buf = it & 1;
      int j0 = it*64;

      floatx4 sac[4];
      #pragma unroll
      for (int jt = 0; jt < 4; jt++) {
        int row = jt*16 + lane15;
        bf16x8 kf0 = *(const bf16x8*)&Ks[buf][row*64 + so];
        bf16x8 kf1 = *(const bf16x8*)&Ks[buf][row*64 + so32];
        sac[jt] = (floatx4){0.f,0.f,0.f,0.f};
        sac[jt] = __builtin_amdgcn_mfma_f32_16x16x32_bf16(kf0, qf0, sac[jt], 0, 0, 0);
        sac[jt] = __builtin_amdgcn_mfma_f32_16x16x32_bf16(kf1, qf1, sac[jt], 0, 0, 0);
      }
      if (j0 + 63 > qrow0) {
        int tokg = qrow0 + lane15;
        #pragma unroll
        for (int jt = 0; jt < 4; jt++)
          #pragma unroll
          for (int r = 0; r < 4; r++) {
            int kv = j0 + jt*16 + laneh*4 + r;
            sac[jt][r] = (kv <= tokg) ? sac[jt][r] * 0.125f : -__builtin_inff();
          }
      } else {
        #pragma unroll
        for (int jt = 0; jt < 4; jt++)
          #pragma unroll
          for (int r = 0; r < 4; r++) sac[jt][r] *= 0.125f;
      }
      float mx = sac[0][0];
      #pragma unroll
      for (int jt = 0; jt < 4; jt++)
        #pragma unroll
        for (int r = 0; r < 4; r++) mx = fmaxf(mx, sac[jt][r]);
      mx = fmaxf(mx, __shfl_xor(mx, 16, 64));
      mx = fmaxf(mx, __shfl_xor(mx, 32, 64));
      float mn = fmaxf(mrow, mx);
      float alpha = __expf(mrow - mn);
      float psum = 0.f;
      #pragma unroll
      for (int jt = 0; jt < 4; jt++)
        #pragma unroll
        for (int r = 0; r < 4; r++) {
          float pv = __expf(sac[jt][r] - mn);
          sac[jt][r] = pv;
          psum += pv;
        }
      psum += __shfl_xor(psum, 16, 64);
      psum += __shfl_xor(psum, 32, 64);
      lrow = lrow * alpha + psum;
      mrow = mn;
      #pragma unroll
      for (int dt = 0; dt < 4; dt++)
        #pragma unroll
        for (int r = 0; r < 4; r++) oacc[dt][r] *= alpha;

      #pragma unroll
      for (int jt = 0; jt < 4; jt++) {
        unsigned int p0 = (unsigned int)f2bf(sac[jt][0]) | ((unsigned int)f2bf(sac[jt][1]) << 16);
        unsigned int p1 = (unsigned int)f2bf(sac[jt][2]) | ((unsigned int)f2bf(sac[jt][3]) << 16);
        int slot = (jt*2 + (laneh >> 1)) ^ (lane15 & 7);
        *(uint2*)&Pw[lane15*64 + slot*8 + (laneh & 1)*4] = make_uint2(p0, p1);
      }
      bf16x8 pf0 = *(const bf16x8*)&Pw[lane15*64 + so];
      bf16x8 pf1 = *(const bf16x8*)&Pw[lane15*64 + so32];
      #pragma unroll
      for (int dt = 0; dt < 4; dt++) {
        int row = dt*16 + lane15;
        bf16x8 vf0 = *(const bf16x8*)&Vts[buf][row*64 + so];
        bf16x8 vf1 = *(const bf16x8*)&Vts[buf][row*64 + so32];
        oacc[dt] = __builtin_amdgcn_mfma_f32_16x16x32_bf16(vf0, pf0, oacc[dt], 0, 0, 0);
        oacc[dt] = __builtin_amdgcn_mfma_f32_16x16x32_bf16(vf1, pf1, oacc[dt], 0, 0, 0);
      }
    }
    float inv = 1.f / lrow;
    unsigned short* orow = ob + (tokbase + qrow0 + lane15)*Cq + h*64 + laneh*4;
    #pragma unroll
    for (int dt = 0; dt < 4; dt++) {
      unsigned int u0 = (unsigned int)f2bf(oacc[dt][0]*inv) | ((unsigned int)f2bf(oacc[dt][1]*inv) << 16);
      unsigned int u1 = (unsigned int)f2bf(oacc[dt][2]*inv) | ((unsigned int)f2bf(oacc[dt][3]*inv) << 16);
      *(uint2*)&orow[dt*16] = make_uint2(u0, u1);
    }
  }
}

// ---------------- lm head prep ----------------
__global__ __launch_bounds__(256) void lmw_prep_kernel(
    const float* __restrict__ lmW, unsigned short* __restrict__ lmWt,
    float* __restrict__ lmWcol)
{
  int idx = blockIdx.x * 256 + threadIdx.x;
  int n = idx & 63, k = idx >> 6;
  lmWt[(size_t)n*Cq + k] = f2bf(lmW[(size_t)k*65 + n]);
  if (idx < Cq) lmWcol[idx] = lmW[(size_t)idx*65 + 64];
}

// ---------------- head: MFMA logits + fused log-softmax + log-sigmoid(dur) ----------------
__global__ __launch_bounds__(64) void head_mfma_kernel(
    const float* __restrict__ x, const unsigned short* __restrict__ lmWt,
    const float* __restrict__ lmWcol, const float* __restrict__ lmb,
    float* __restrict__ out)
{
  int lane = threadIdx.x;
  int lane15 = lane & 15, laneh = lane >> 4;
  int tok0 = blockIdx.x * 16;

  floatx4 acc[4];
  #pragma unroll
  for (int jt = 0; jt < 4; jt++) acc[jt] = (floatx4){0.f,0.f,0.f,0.f};

  const float* xrow = x + (size_t)(tok0 + lane15) * Cq + laneh*8;
  const unsigned short* brow = lmWt + (size_t)lane15 * Cq + laneh*8;

  for (int k0 = 0; k0 < Cq; k0 += 32) {
    float4 a0 = *(const float4*)(xrow + k0);
    float4 a1 = *(const float4*)(xrow + k0 + 4);
    bf16x8 af;
    af[0] = (__bf16)a0.x; af[1] = (__bf16)a0.y; af[2] = (__bf16)a0.z; af[3] = (__bf16)a0.w;
    af[4] = (__bf16)a1.x; af[5] = (__bf16)a1.y; af[6] = (__bf16)a1.z; af[7] = (__bf16)a1.w;
    #pragma unroll
    for (int jt = 0; jt < 4; jt++) {
      bf16x8 bfv = *(const bf16x8*)(brow + (size_t)jt*16*Cq + k0);
      acc[jt] = __builtin_amdgcn_mfma_f32_16x16x32_bf16(af, bfv, acc[jt], 0, 0, 0);
    }
  }
  #pragma unroll
  for (int jt = 0; jt < 4; jt++) {
    float bias = lmb[jt*16 + lane15];
    #pragma unroll
    for (int r = 0; r < 4; r++) acc[jt][r] += bias;
  }
  #pragma unroll
  for (int r = 0; r < 4; r++) {
    float m = fmaxf(fmaxf(acc[0][r], acc[1][r]), fmaxf(acc[2][r], acc[3][r]));
    #pragma unroll
    for (int s = 1; s < 16; s <<= 1) m = fmaxf(m, __shfl_xor(m, s, 64));
    float se = 0.f;
    #pragma unroll
    for (int jt = 0; jt < 4; jt++) se += expf(acc[jt][r] - m);
    #pragma unroll
    for (int s = 1; s < 16; s <<= 1) se += __shfl_xor(se, s, 64);
    float lse = m + logf(se);
    int tok = tok0 + laneh*4 + r;
    float* orow = out + (size_t)tok * 65;
    #pragma unroll
    for (int jt = 0; jt < 4; jt++)
      orow[jt*16 + lane15] = acc[jt][r] - lse;
  }
  int t = lane >> 2, kq = (lane & 3) * 256;
  const float* xr2 = x + (size_t)(tok0 + t) * Cq + kq;
  const float* wc = lmWcol + kq;
  float s = 0.f;
  #pragma unroll 4
  for (int i = 0; i < 256; i += 4) {
    float4 xv = *(const float4*)(xr2 + i);
    float4 wv = *(const float4*)(wc + i);
    s += xv.x*wv.x + xv.y*wv.y + xv.z*wv.z + xv.w*wv.w;
  }
  s += __shfl_xor(s, 1, 64);
  s += __shfl_xor(s, 2, 64);
  if ((lane & 3) == 0) {
    float z = s + lmb[64];
    float ls = (z >= 0.f) ? -log1pf(expf(-z)) : (z - log1pf(expf(z)));
    out[(size_t)(tok0 + t) * 65 + 64] = ls;
  }
}

extern "C" void kernel_launch(void* const* d_in, const int* in_sizes, int n_in,
                              void* d_out, int out_size, void* d_ws, size_t ws_size,
                              hipStream_t stream) {
  const int*   acts = (const int*)  d_in[0];
  const float* dur  = (const float*)d_in[1];
  const float* emb  = (const float*)d_in[2];
  const float* pos  = (const float*)d_in[3];
  const float* Wq   = (const float*)d_in[4];
  const float* Wk   = (const float*)d_in[5];
  const float* Wv   = (const float*)d_in[6];
  const float* Wo   = (const float*)d_in[7];
  const float* bo   = (const float*)d_in[8];
  const float* W1   = (const float*)d_in[9];
  const float* b1   = (const float*)d_in[10];
  const float* W2   = (const float*)d_in[11];
  const float* b2   = (const float*)d_in[12];
  const float* g1   = (const float*)d_in[13];
  const float* g2   = (const float*)d_in[14];
  const float* lmW  = (const float*)d_in[15];
  const float* lmb  = (const float*)d_in[16];
  float* out = (float*)d_out;
  (void)in_sizes; (void)n_in; (void)out_size; (void)ws_size;

  char* w = (char*)d_ws;
  auto take = [&](size_t bytes) { char* p = w; w += (bytes + 255) & ~(size_t)255; return p; };
  unsigned short* qk  = (unsigned short*)take((size_t)BT*2048*2);
  unsigned short* vT  = (unsigned short*)take((size_t)Bq*Hq*Dq*Tq*2);
  unsigned short* ob  = (unsigned short*)take((size_t)BT*Cq*2);
  unsigned short* m1  = qk;                      // FF1 out aliases qk+vT+ob (32 MB)
  unsigned short* hb  = (unsigned short*)take((size_t)BT*Cq*2);
  float*          x   = (float*)take((size_t)BT*Cq*4);
  unsigned short* wqkvl = (unsigned short*)take((size_t)3072*Cq*2);
  unsigned short* wol   = (unsigned short*)take((size_t)Cq*Cq*2);
  unsigned short* w1l   = (unsigned short*)take((size_t)Fq*Cq*2);
  unsigned short* w2l   = (unsigned short*)take((size_t)Cq*Fq*2);
  unsigned short* lmWt  = (unsigned short*)take((size_t)64*Cq*2);
  float*          lmWcol= (float*)take((size_t)Cq*4);
  float*          part  = (float*)take((size_t)2*BT*Cq*4);   // split-K partials (32 MB)

  dim3 tb(32, 8);
  embed_kernel<<<BT, 256, 0, stream>>>(acts, dur, emb, pos, x);
  lmw_prep_kernel<<<256, 256, 0, stream>>>(lmW, lmWt, lmWcol);

  for (int l = 0; l < Lq; l++) {
    prep_layer_kernel<<<12288, tb, 0, stream>>>(
        Wq + (size_t)l*Hq*Cq*Dq, Wk + (size_t)l*Hq*Cq*Dq, Wv + (size_t)l*Hq*Cq*Dq,
        Wo + (size_t)l*Cq*Cq, W1 + (size_t)l*Cq*Fq, W2 + (size_t)l*Fq*Cq,
        wqkvl, wol, w1l, w2l);

    rmsnorm_kernel<<<BT, 256, 0, stream>>>(x, g1 + l*Cq, hb);
    gemm_bt_kernel<0><<<dim3(24,32), 256, 0, stream>>>(
        hb, Cq, wqkvl, Cq, Cq, qk, 2048, vT, nullptr, 0, nullptr);
    attn_kernel<<<Bq*Hq*8, 256, 0, stream>>>(qk, vT, ob);
    gemm_bt_kernel<2><<<dim3(8,32), 256, 0, stream>>>(
        ob, Cq, wol, Cq, Cq, nullptr, 0, nullptr, x, Cq, bo + l*Cq);
    rmsnorm_kernel<<<BT, 256, 0, stream>>>(x, g2 + l*Cq, hb);

    // SHADOW experiment (layer 0 only): 256^2 4-phase reg-staged GEMM into
    // scratch (part). Output unused — legacy FF1 below is authoritative.
    // Readout: its dur_us in the profile (top-5 presence <=> still slow).
    if (l == 0)
      gemm256r_kernel<<<dim3(16,16), 512, 0, stream>>>(
          hb, Cq, w1l, Cq, Cq, (unsigned short*)part, Fq, b1);

    gemm_bt_kernel<1><<<dim3(32,32), 256, 0, stream>>>(
        hb, Cq, w1l, Cq, Cq, m1, Fq, nullptr, nullptr, 0, b1 + l*Fq);
    gemm_bt_kernel<3><<<dim3(8,32,2), 256, 0, stream>>>(
        m1, Fq, w2l, Fq, 2048, nullptr, 0, nullptr, part, Cq, nullptr);
    splitk_reduce_kernel<<<BT*Cq/1024, 256, 0, stream>>>(part, x, b2 + l*Cq);
  }
  head_mfma_kernel<<<BT/16, 64, 0, stream>>>(x, lmWt, lmWcol, lmb, out);
}

// Round 6
// 1176.791 us; speedup vs baseline: 1.0668x; 1.0589x over previous
//
#include <hip/hip_runtime.h>

// Problem constants
#define Bq 4
#define Tq 1024
#define Cq 1024
#define Hq 16
#define Dq 64
#define Fq 4096
#define Lq 4
#define BT (Bq*Tq)

typedef __attribute__((ext_vector_type(8))) __bf16 bf16x8;
typedef __attribute__((ext_vector_type(4))) float  floatx4;

__device__ __forceinline__ unsigned short f2bf(float f) {
  unsigned int u = __builtin_bit_cast(unsigned int, f);
  u = (u + 0x7FFFu + ((u >> 16) & 1u)) >> 16;   // RNE
  return (unsigned short)u;
}

// async global->LDS, 16B per lane; lds ptr must be wave-uniform (HW adds lane*16)
__device__ __forceinline__ void gld_lds16(const void* g, void* lds) {
  __builtin_amdgcn_global_load_lds(
      (const __attribute__((address_space(1))) unsigned int*)g,
      (__attribute__((address_space(3))) unsigned int*)lds, 16, 0, 0);
}

// partial-drain barrier used by the legacy 128^2 kernel (measured-good)
__device__ __forceinline__ void barrier_vmcnt4() {
  asm volatile("s_waitcnt vmcnt(4)\n\ts_barrier" ::: "memory");
}

// full LDS-sync barrier for the 256^2 kernel: drain this wave's LDS ops,
// then barrier => at each barrier every wave's phase reads AND writes are
// retired. "memory" clobber gives IR-level ordering (r2==r3 showed it costs
// nothing); sched_barrier(0) pins the machine scheduler (rule #18).
__device__ __forceinline__ void tbar_lds() {
  __builtin_amdgcn_sched_barrier(0);
  asm volatile("s_waitcnt lgkmcnt(0)\n\ts_barrier" ::: "memory");
  __builtin_amdgcn_sched_barrier(0);
}

// ---------------- embed: x = concat(emb[acts], dur) + pos ----------------
__global__ __launch_bounds__(256) void embed_kernel(
    const int* __restrict__ acts, const float* __restrict__ dur,
    const float* __restrict__ emb, const float* __restrict__ pos,
    float* __restrict__ x)
{
  int tok = blockIdx.x;
  int t = tok & (Tq-1);
  int a = acts[tok];
  const float* er = emb + (size_t)a * (Cq-1);
  const float* pr = pos + (size_t)t * Cq;
  float* xr = x + (size_t)tok * Cq;
  float dv = dur[tok];
  for (int c = threadIdx.x; c < Cq; c += 256) {
    float v = (c < Cq-1) ? er[c] : dv;
    xr[c] = v + pr[c];
  }
}

// ---------------- rmsnorm -> bf16 ----------------
__global__ __launch_bounds__(256) void rmsnorm_kernel(
    const float* __restrict__ x, const float* __restrict__ g,
    unsigned short* __restrict__ h)
{
  int tok = blockIdx.x, tid = threadIdx.x;
  const float4* xr = (const float4*)(x + (size_t)tok * Cq);
  float4 v = xr[tid];
  float ss = v.x*v.x + v.y*v.y + v.z*v.z + v.w*v.w;
  #pragma unroll
  for (int s = 32; s >= 1; s >>= 1) ss += __shfl_xor(ss, s, 64);
  __shared__ float ws4[4];
  if ((tid & 63) == 0) ws4[tid >> 6] = ss;
  __syncthreads();
  float tot = ws4[0] + ws4[1] + ws4[2] + ws4[3];
  float r = rsqrtf(tot * (1.0f/(float)Cq) + 1.1920928955078125e-07f);
  float4 gv = ((const float4*)g)[tid];
  unsigned short o4[4] = { f2bf(v.x*r*gv.x), f2bf(v.y*r*gv.y),
                           f2bf(v.z*r*gv.z), f2bf(v.w*r*gv.w) };
  *(uint2*)(h + (size_t)tok*Cq + tid*4) = *(const uint2*)o4;
}

// ---------------- fused per-layer weight prep: all 6 transposes in 1 launch ----------------
__global__ void prep_layer_kernel(
    const float* __restrict__ Wq, const float* __restrict__ Wk,
    const float* __restrict__ Wv, const float* __restrict__ Wo,
    const float* __restrict__ W1, const float* __restrict__ W2,
    unsigned short* __restrict__ wqkvl, unsigned short* __restrict__ wol,
    unsigned short* __restrict__ w1l,   unsigned short* __restrict__ w2l)
{
  __shared__ float tile[32][33];
  int z = blockIdx.x;
  const float* in; unsigned short* out;
  int R, Cc, tx, ty;
  if (z < 3072) {
    int i = z >> 10, t = z & 1023;
    int hh = t >> 6, rem = t & 63;
    ty = rem >> 1; tx = rem & 1;
    const float* w = (i == 0) ? Wq : (i == 1) ? Wk : Wv;
    in = w + (size_t)hh * Cq * Dq;
    out = wqkvl + (size_t)i * 1024 * 1024 + (size_t)hh * 64 * 1024;
    R = 1024; Cc = 64;
  } else if (z < 4096) {
    int t = z - 3072;
    tx = t & 31; ty = t >> 5;
    in = Wo; out = wol; R = 1024; Cc = 1024;
  } else if (z < 8192) {
    int t = z - 4096;
    tx = t & 127; ty = t >> 7;
    in = W1; out = w1l; R = 1024; Cc = 4096;
  } else {
    int t = z - 8192;
    tx = t & 31; ty = t >> 5;
    in = W2; out = w2l; R = 4096; Cc = 1024;
  }
  int c0 = tx * 32, r0 = ty * 32;
  int lx = threadIdx.x, ly = threadIdx.y;  // 32 x 8
  #pragma unroll
  for (int i = 0; i < 32; i += 8)
    tile[ly+i][lx] = in[(size_t)(r0+ly+i)*Cc + c0 + lx];
  __syncthreads();
  #pragma unroll
  for (int i = 0; i < 32; i += 8)
    out[(size_t)(c0+ly+i)*R + r0 + lx] = f2bf(tile[lx][ly+i]);
}

// ---------------- legacy 128^2 GEMM (QKV: EPI 0, Wo: EPI 2, FF2: EPI 3) ----
// Round-0 exact mapping (XCD swizzle removed: measured regression, r5:
// FETCH 41->70 MB, dur +3.2us on FF1).
template <int EPI>
__global__ __launch_bounds__(256)
void gemm_bt_kernel(const unsigned short* __restrict__ A, int lda,
                    const unsigned short* __restrict__ Bt, int ldb,
                    int KS,
                    unsigned short* __restrict__ outB, int ldc,
                    unsigned short* __restrict__ vT,
                    float* __restrict__ outF, int ldf,
                    const float* __restrict__ bias)
{
  __shared__ unsigned short lds_a[3*4096];
  __shared__ unsigned short lds_b[3*4096];
  int tid = threadIdx.x;
  int lane = tid & 63, wv = tid >> 6;
  int lane15 = lane & 15, laneh = lane >> 4;
  int m0 = blockIdx.y * 128, n0 = blockIdx.x * 128;
  int wm = wv & 1, wn = wv >> 1;

  floatx4 acc[4][4];
  #pragma unroll
  for (int i = 0; i < 4; i++)
    #pragma unroll
    for (int j = 0; j < 4; j++) acc[i][j] = (floatx4){0.f,0.f,0.f,0.f};

  int seg0 = (wv*2+0)*64 + lane;
  int seg1 = (wv*2+1)*64 + lane;
  int ra0 = seg0 >> 2, ca0 = ((seg0 & 3) ^ (ra0 & 3)) * 8;
  int ra1 = seg1 >> 2, ca1 = ((seg1 & 3) ^ (ra1 & 3)) * 8;
  const unsigned short* a_src0 = A  + (size_t)(m0+ra0)*lda + ca0;
  const unsigned short* a_src1 = A  + (size_t)(m0+ra1)*lda + ca1;
  const unsigned short* b_src0 = Bt + (size_t)(n0+ra0)*ldb + ca0;
  const unsigned short* b_src1 = Bt + (size_t)(n0+ra1)*ldb + ca1;
  unsigned short* a_dst0 = &lds_a[(wv*2+0)*512];
  unsigned short* a_dst1 = &lds_a[(wv*2+1)*512];
  unsigned short* b_dst0 = &lds_b[(wv*2+0)*512];
  unsigned short* b_dst1 = &lds_b[(wv*2+1)*512];

  int sx = (laneh ^ (lane15 & 3)) * 8;

  int kbeg = (EPI == 3) ? blockIdx.z * KS : 0;
  int nIter = KS >> 5;

  auto stage = [&](int k0, int buf) {
    int off = buf * 4096;
    gld_lds16(a_src0 + k0, a_dst0 + off);
    gld_lds16(a_src1 + k0, a_dst1 + off);
    gld_lds16(b_src0 + k0, b_dst0 + off);
    gld_lds16(b_src1 + k0, b_dst1 + off);
  };

  stage(kbeg, 0);
  stage(kbeg + 32, 1);
  int cb = 0, pb = 2;
  for (int it = 0; it < nIter; ++it) {
    barrier_vmcnt4();
    if (it + 2 < nIter) stage(kbeg + (it+2)*32, pb);
    const unsigned short* la = &lds_a[cb*4096];
    const unsigned short* lb = &lds_b[cb*4096];
    bf16x8 af[4], bf[4];
    #pragma unroll
    for (int i = 0; i < 4; i++)
      af[i] = *(const bf16x8*)&la[(wm*64 + i*16 + lane15)*32 + sx];
    #pragma unroll
    for (int j = 0; j < 4; j++)
      bf[j] = *(const bf16x8*)&lb[(wn*64 + j*16 + lane15)*32 + sx];
    #pragma unroll
    for (int i = 0; i < 4; i++)
      #pragma unroll
      for (int j = 0; j < 4; j++)
        acc[i][j] = __builtin_amdgcn_mfma_f32_16x16x32_bf16(af[i], bf[j], acc[i][j], 0, 0, 0);
    cb = (cb == 2) ? 0 : cb + 1;
    pb = (pb == 2) ? 0 : pb + 1;
  }

  float* outFz = (EPI == 3) ? outF + (size_t)blockIdx.z * BT * Cq : outF;

  #pragma unroll
  for (int i = 0; i < 4; i++) {
    int row = m0 + wm*64 + i*16 + laneh*4;
    #pragma unroll
    for (int j = 0; j < 4; j++) {
      int col = n0 + wn*64 + j*16 + lane15;
      #pragma unroll
      for (int r = 0; r < 4; r++) {
        float v = acc[i][j][r];
        int rr = row + r;
        if constexpr (EPI == 0) {
          if (col < 2048) {
            outB[(size_t)rr*ldc + col] = f2bf(v);
          } else {
            int b = rr >> 10, t = rr & (Tq-1);
            int hd = col - 2048, hh = hd >> 6, d = hd & 63;
            vT[(((size_t)b*Hq + hh)*Dq + d)*Tq + t] = f2bf(v);
          }
        } else if constexpr (EPI == 1) {
          float z = v + bias[col];
          float u = 0.79788456080286536f * (z + 0.044715f * z*z*z);
          float t = 1.f - 2.f / (__expf(2.f*u) + 1.f);
          float gl = 0.5f * z * (1.f + t);
          outB[(size_t)rr*ldc + col] = f2bf(gl);
        } else if constexpr (EPI == 2) {
          outF[(size_t)rr*ldf + col] += v + bias[col];
        } else {
          outFz[(size_t)rr*ldf + col] = v;
        }
      }
    }
  }
}

// ---------------- 256^2 4-phase GEMM, reg-staged, v4 (FF1 authoritative) ----
// Staging global->VGPR->ds_write (bf16x8-typed both sides). ONE full-LDS-sync
// barrier per phase (tbar_lds). Per-tile writes:
//   P1: B-lo(t+1)->buf^1   P2: A-lo(t+2)->buf
//   P3: B-hi(t+2)->buf     P4: A-hi(t+2)->buf
// => tile t+1's {A-lo,B-hi,A-hi} come from tile t-1's P2/P3/P4. Therefore the
// PROLOGUE must stage tile0 (all 4 regions, buf0) AND tile1's A-lo/B-hi/A-hi
// (buf1). <-- r4's absmax-21.9 bug: these three writes were missing. Fixed.
// Register pairs: X cycles P1(wr)->P1(ld B-hi t+2)->P3(wr)->P3(ld B-lo t+2);
// Y cycles P2(wr)->P2(ld A-hi t+2)->P4(wr)->P4(ld A-lo t+3). Loads issue ~2
// phases before their ds_write (T14); compiler inserts precise counted vmcnt.
// Region race ledger (each write >=1 barrier after last read, verified):
//   B-lo[buf^1]: last read P4(t-1) | write P1(t) | next read P1(t+1)
//   A-lo[buf]  : last read P1(t)   | write P2(t) | next read P1(t+2)
//   B-hi[buf]  : last read P2(t)   | write P3(t) | next read P2(t+2)
//   A-hi[buf]  : last read P3(t)   | write P4(t) | next read P3(t+2)
// Swizzle on the write side: LDS granule p of row r holds global granule
// p^(r&7); frag reads use (laneh^(lane15&7)) — image identical to the
// refcheck-verified r2 DMA version. Gelu epilogue.
__global__ __launch_bounds__(512, 2)
void gemm256r_kernel(const unsigned short* __restrict__ A, int lda,
                     const unsigned short* __restrict__ Bt, int ldb,
                     int KS,
                     unsigned short* __restrict__ outB, int ldc,
                     const float* __restrict__ bias)
{
  __shared__ unsigned short lds_a[2][256*64];
  __shared__ unsigned short lds_b[2][256*64];
  const int tid = threadIdx.x;
  const int lane = tid & 63, wv = tid >> 6;
  const int lane15 = lane & 15, laneh = lane >> 4;
  const int wm = wv & 1, wn = wv >> 1;      // 2 x 4 waves

  const int m0 = (int)blockIdx.y * 256, n0 = (int)blockIdx.x * 256;
  const int nT = KS >> 6;

  const int rowS = tid >> 3;
  const int gS  = tid & 7;
  const int swz = (gS ^ (rowS & 7)) * 8;    // write-side XOR swizzle

  auto ldA = [&](int kt, int h, bf16x8& r0, bf16x8& r1) {
    const unsigned short* s = A + (size_t)(m0 + h*128 + rowS)*lda + kt*64 + gS*8;
    r0 = *(const bf16x8*)s;
    r1 = *(const bf16x8*)(s + (size_t)64*lda);
  };
  auto ldB = [&](int kt, int h, bf16x8& r0, bf16x8& r1) {
    const unsigned short* s = Bt + (size_t)(n0 + h*128 + rowS)*ldb + kt*64 + gS*8;
    r0 = *(const bf16x8*)s;
    r1 = *(const bf16x8*)(s + (size_t)64*ldb);
  };
  auto wrA = [&](int h, int b, bf16x8 r0, bf16x8 r1) {
    unsigned short* d = &lds_a[b][(h*128 + rowS)*64 + swz];
    *(bf16x8*)d = r0;
    *(bf16x8*)(d + 64*64) = r1;   // row+64: same (row&7) => same swizzle
  };
  auto wrB = [&](int h, int b, bf16x8 r0, bf16x8 r1) {
    unsigned short* d = &lds_b[b][(h*128 + rowS)*64 + swz];
    *(bf16x8*)d = r0;
    *(bf16x8*)(d + 64*64) = r1;
  };

  const int soff0 = ((laneh)     ^ (lane15 & 7)) * 8;   // ks=0 granules 0..3
  const int soff1 = ((4 + laneh) ^ (lane15 & 7)) * 8;   // ks=1 granules 4..7
  const int arow = (wm*16 + lane15) * 64;
  const int brow = (wn*16 + lane15) * 64;

  floatx4 acc[8][4];
  #pragma unroll
  for (int i = 0; i < 8; i++)
    #pragma unroll
    for (int j = 0; j < 4; j++) acc[i][j] = (floatx4){0.f,0.f,0.f,0.f};

  bf16x8 af[4][2], bfr[2][2];
  bf16x8 sX0, sX1, sY0, sY1;

  // ---- prologue (fixed): tile0 -> buf0 (all), tile1 A-lo/B-hi/A-hi -> buf1,
  // then prime sX = B-lo(1), sY = A-lo(2).
  ldA(0, 0, sX0, sX1); ldB(0, 0, sY0, sY1);
  wrA(0, 0, sX0, sX1); wrB(0, 0, sY0, sY1);
  ldA(0, 1, sX0, sX1); ldB(0, 1, sY0, sY1);
  wrA(1, 0, sX0, sX1); wrB(1, 0, sY0, sY1);
  if (nT > 1) {
    ldA(1, 0, sX0, sX1); ldB(1, 1, sY0, sY1);
    wrA(0, 1, sX0, sX1); wrB(1, 1, sY0, sY1);
    ldA(1, 1, sX0, sX1);
    wrA(1, 1, sX0, sX1);
    ldB(1, 0, sX0, sX1);               // prime sX = B-lo(1)
  }
  if (nT > 2) ldA(2, 0, sY0, sY1);     // prime sY = A-lo(2)
  tbar_lds();

  for (int t = 0; t < nT; ++t) {
    const int buf = t & 1;
    const unsigned short* la = &lds_a[buf][0];
    const unsigned short* lb = &lds_b[buf][0];

    // ---- P1: (A-lo, B-lo) ----
    #pragma unroll
    for (int ii = 0; ii < 4; ii++) {
      af[ii][0] = *(const bf16x8*)&la[arow + ii*2048 + soff0];
      af[ii][1] = *(const bf16x8*)&la[arow + ii*2048 + soff1];
    }
    #pragma unroll
    for (int jj = 0; jj < 2; jj++) {
      bfr[jj][0] = *(const bf16x8*)&lb[brow + jj*4096 + soff0];
      bfr[jj][1] = *(const bf16x8*)&lb[brow + jj*4096 + soff1];
    }
    if (t + 1 < nT) wrB(0, buf^1, sX0, sX1);   // B-lo(t+1)
    if (t + 2 < nT) ldB(t+2, 1, sX0, sX1);     // B-hi(t+2) -> X
    __builtin_amdgcn_s_setprio(1);
    #pragma unroll
    for (int ks = 0; ks < 2; ks++)
      #pragma unroll
      for (int ii = 0; ii < 4; ii++)
        #pragma unroll
        for (int jj = 0; jj < 2; jj++)
          acc[ii][jj] = __builtin_amdgcn_mfma_f32_16x16x32_bf16(af[ii][ks], bfr[jj][ks], acc[ii][jj], 0, 0, 0);
    __builtin_amdgcn_s_setprio(0);
    tbar_lds();

    // ---- P2: (A-lo, B-hi) — af reused ----
    #pragma unroll
    for (int jj = 0; jj < 2; jj++) {
      bfr[jj][0] = *(const bf16x8*)&lb[8192 + brow + jj*4096 + soff0];
      bfr[jj][1] = *(const bf16x8*)&lb[8192 + brow + jj*4096 + soff1];
    }
    if (t + 2 < nT) wrA(0, buf, sY0, sY1);     // A-lo(t+2)
    if (t + 2 < nT) ldA(t+2, 1, sY0, sY1);     // A-hi(t+2) -> Y
    __builtin_amdgcn_s_setprio(1);
    #pragma unroll
    for (int ks = 0; ks < 2; ks++)
      #pragma unroll
      for (int ii = 0; ii < 4; ii++)
        #pragma unroll
        for (int jj = 0; jj < 2; jj++)
          acc[ii][2+jj] = __builtin_amdgcn_mfma_f32_16x16x32_bf16(af[ii][ks], bfr[jj][ks], acc[ii][2+jj], 0, 0, 0);
    __builtin_amdgcn_s_setprio(0);
    tbar_lds();

    // ---- P3: (A-hi, B-hi) — bfr reused ----
    #pragma unroll
    for (int ii = 0; ii < 4; ii++) {
      af[ii][0] = *(const bf16x8*)&la[8192 + arow + ii*2048 + soff0];
      af[ii][1] = *(const bf16x8*)&la[8192 + arow + ii*2048 + soff1];
    }
    if (t + 2 < nT) wrB(1, buf, sX0, sX1);     // B-hi(t+2)
    if (t + 2 < nT) ldB(t+2, 0, sX0, sX1);     // B-lo(t+2) -> X
    __builtin_amdgcn_s_setprio(1);
    #pragma unroll
    for (int ks = 0; ks < 2; ks++)
      #pragma unroll
      for (int ii = 0; ii < 4; ii++)
        #pragma unroll
        for (int jj = 0; jj < 2; jj++)
          acc[4+ii][2+jj] = __builtin_amdgcn_mfma_f32_16x16x32_bf16(af[ii][ks], bfr[jj][ks], acc[4+ii][2+jj], 0, 0, 0);
    __builtin_amdgcn_s_setprio(0);
    tbar_lds();

    // ---- P4: (A-hi, B-lo) — af reused, B-lo re-read ----
    #pragma unroll
    for (int jj = 0; jj < 2; jj++) {
      bfr[jj][0] = *(const bf16x8*)&lb[brow + jj*4096 + soff0];
      bfr[jj][1] = *(const bf16x8*)&lb[brow + jj*4096 + soff1];
    }
    if (t + 2 < nT) wrA(1, buf, sY0, sY1);     // A-hi(t+2)
    if (t + 3 < nT) ldA(t+3, 0, sY0, sY1);     // A-lo(t+3) -> Y
    __builtin_amdgcn_s_setprio(1);
    #pragma unroll
    for (int ks = 0; ks < 2; ks++)
      #pragma unroll
      for (int ii = 0; ii < 4; ii++)
        #pragma unroll
        for (int jj = 0; jj < 2; jj++)
          acc[4+ii][jj] = __builtin_amdgcn_mfma_f32_16x16x32_bf16(af[ii][ks], bfr[jj][ks], acc[4+ii][jj], 0, 0, 0);
    __builtin_amdgcn_s_setprio(0);
    tbar_lds();
  }

  #pragma unroll
  for (int i = 0; i < 8; i++) {
    int row = m0 + (i>>2)*128 + (i&3)*32 + wm*16 + laneh*4;
    #pragma unroll
    for (int j = 0; j < 4; j++) {
      int col = n0 + (j>>1)*128 + (j&1)*64 + wn*16 + lane15;
      #pragma unroll
      for (int r = 0; r < 4; r++) {
        float v = acc[i][j][r];
        int rr = row + r;
        float z = v + bias[col];
        float u = 0.79788456080286536f * (z + 0.044715f * z*z*z);
        float tt = 1.f - 2.f / (__expf(2.f*u) + 1.f);
        float gl = 0.5f * z * (1.f + tt);
        outB[(size_t)rr*ldc + col] = f2bf(gl);
      }
    }
  }
}

// ---------------- split-K reduce: x += p0 + p1 + bias ----------------
__global__ __launch_bounds__(256) void splitk_reduce_kernel(
    const float* __restrict__ p, float* __restrict__ x,
    const float* __restrict__ bias)
{
  size_t o = ((size_t)blockIdx.x * 256 + threadIdx.x) * 4;
  float4 a = *(const float4*)(p + o);
  float4 b = *(const float4*)(p + (size_t)BT*Cq + o);
  float4 xv = *(const float4*)(x + o);
  float4 bi = *(const float4*)(bias + (o & (Cq-1)));
  xv.x += a.x + b.x + bi.x;
  xv.y += a.y + b.y + bi.y;
  xv.z += a.z + b.z + bi.z;
  xv.w += a.w + b.w + bi.w;
  *(float4*)(x + o) = xv;
}

// ---------------- flash attention (causal), S^T form (R6-verified) ----------------
__global__ __launch_bounds__(256)
void attn_kernel(const unsigned short* __restrict__ qk,   // (BT,2048): q 0..1023, k 1024..2047
                 const unsigned short* __restrict__ vT,   // (B,H,D,T)
                 unsigned short* __restrict__ ob)         // (BT,1024)
{
  __shared__ unsigned short Ks [2][64*64];
  __shared__ unsigned short Vts[2][64*64];
  __shared__ unsigned short Ps [4*16*64];
  int tid = threadIdx.x, lane = tid & 63, wv = tid >> 6;
  int lane15 = lane & 15, laneh = lane >> 4;
  int blk = blockIdx.x;
  int p = blk & 7, bh = blk >> 3;
  int h = bh & (Hq-1), b = bh >> 4;
  size_t tokbase = (size_t)b * Tq;
  const unsigned short* Kbase = qk + tokbase*2048 + 1024 + h*64;
  const unsigned short* Vbase = vT + (size_t)bh * Dq * Tq;

  int so  = (laneh ^ (lane15 & 7)) * 8;
  int so32 = so ^ 32;
  unsigned short* Pw = &Ps[wv*1024];

  auto stage = [&](int j0, int buf) {
    #pragma unroll
    for (int i = 0; i < 2; i++) {
      int seg = (wv*2+i)*64 + lane;
      int row = seg >> 3;
      int col = ((seg & 7) ^ (row & 7)) * 8;
      gld_lds16(Kbase + (size_t)(j0+row)*2048 + col, &Ks [buf][(wv*2+i)*512]);
      gld_lds16(Vbase + (size_t)row*Tq + j0 + col,   &Vts[buf][(wv*2+i)*512]);
    }
  };

  for (int phase = 0; phase < 2; ++phase) {
    int qt = phase ? (15 - p) : p;
    int qrow0 = qt*64 + wv*16;
    bf16x8 qf0, qf1;
    {
      const unsigned short* qp = qk + (tokbase + qrow0 + lane15)*2048 + h*64 + laneh*8;
      qf0 = *(const bf16x8*)(qp);
      qf1 = *(const bf16x8*)(qp + 32);
    }
    floatx4 oacc[4];
    #pragma unroll
    for (int d = 0; d < 4; d++) oacc[d] = (floatx4){0.f,0.f,0.f,0.f};
    float mrow = -__builtin_inff(), lrow = 0.f;
    int nT = qt + 1;

    __syncthreads();
    stage(0, 0);
    for (int it = 0; it < nT; ++it) {
      __syncthreads();
      if (it + 1 < nT) stage((it+1)*64, (it+1) & 1);
      int buf = it & 1;
      int j0 = it*64;

      floatx4 sac[4];
      #pragma unroll
      for (int jt = 0; jt < 4; jt++) {
        int row = jt*16 + lane15;
        bf16x8 kf0 = *(const bf16x8*)&Ks[buf][row*64 + so];
        bf16x8 kf1 = *(const bf16x8*)&Ks[buf][row*64 + so32];
        sac[jt] = (floatx4){0.f,0.f,0.f,0.f};
        sac[jt] = __builtin_amdgcn_mfma_f32_16x16x32_bf16(kf0, qf0, sac[jt], 0, 0, 0);
        sac[jt] = __builtin_amdgcn_mfma_f32_16x16x32_bf16(kf1, qf1, sac[jt], 0, 0, 0);
      }
      if (j0 + 63 > qrow0) {
        int tokg = qrow0 + lane15;
        #pragma unroll
        for (int jt = 0; jt < 4; jt++)
          #pragma unroll
          for (int r = 0; r < 4; r++) {
            int kv = j0 + jt*16 + laneh*4 + r;
            sac[jt][r] = (kv <= tokg) ? sac[jt][r] * 0.125f : -__builtin_inff();
          }
      } else {
        #pragma unroll
        for (int jt = 0; jt < 4; jt++)
          #pragma unroll
          for (int r = 0; r < 4; r++) sac[jt][r] *= 0.125f;
      }
      float mx = sac[0][0];
      #pragma unroll
      for (int jt = 0; jt < 4; jt++)
        #pragma unroll
        for (int r = 0; r < 4; r++) mx = fmaxf(mx, sac[jt][r]);
      mx = fmaxf(mx, __shfl_xor(mx, 16, 64));
      mx = fmaxf(mx, __shfl_xor(mx, 32, 64));
      float mn = fmaxf(mrow, mx);
      float alpha = __expf(mrow - mn);
      float psum = 0.f;
      #pragma unroll
      for (int jt = 0; jt < 4; jt++)
        #pragma unroll
        for (int r = 0; r < 4; r++) {
          float pv = __expf(sac[jt][r] - mn);
          sac[jt][r] = pv;
          psum += pv;
        }
      psum += __shfl_xor(psum, 16, 64);
      psum += __shfl_xor(psum, 32, 64);
      lrow = lrow * alpha + psum;
      mrow = mn;
      #pragma unroll
      for (int dt = 0; dt < 4; dt++)
        #pragma unroll
        for (int r = 0; r < 4; r++) oacc[dt][r] *= alpha;

      #pragma unroll
      for (int jt = 0; jt < 4; jt++) {
        unsigned int p0 = (unsigned int)f2bf(sac[jt][0]) | ((unsigned int)f2bf(sac[jt][1]) << 16);
        unsigned int p1 = (unsigned int)f2bf(sac[jt][2]) | ((unsigned int)f2bf(sac[jt][3]) << 16);
        int slot = (jt*2 + (laneh >> 1)) ^ (lane15 & 7);
        *(uint2*)&Pw[lane15*64 + slot*8 + (laneh & 1)*4] = make_uint2(p0, p1);
      }
      bf16x8 pf0 = *(const bf16x8*)&Pw[lane15*64 + so];
      bf16x8 pf1 = *(const bf16x8*)&Pw[lane15*64 + so32];
      #pragma unroll
      for (int dt = 0; dt < 4; dt++) {
        int row = dt*16 + lane15;
        bf16x8 vf0 = *(const bf16x8*)&Vts[buf][row*64 + so];
        bf16x8 vf1 = *(const bf16x8*)&Vts[buf][row*64 + so32];
        oacc[dt] = __builtin_amdgcn_mfma_f32_16x16x32_bf16(vf0, pf0, oacc[dt], 0, 0, 0);
        oacc[dt] = __builtin_amdgcn_mfma_f32_16x16x32_bf16(vf1, pf1, oacc[dt], 0, 0, 0);
      }
    }
    float inv = 1.f / lrow;
    unsigned short* orow = ob + (tokbase + qrow0 + lane15)*Cq + h*64 + laneh*4;
    #pragma unroll
    for (int dt = 0; dt < 4; dt++) {
      unsigned int u0 = (unsigned int)f2bf(oacc[dt][0]*inv) | ((unsigned int)f2bf(oacc[dt][1]*inv) << 16);
      unsigned int u1 = (unsigned int)f2bf(oacc[dt][2]*inv) | ((unsigned int)f2bf(oacc[dt][3]*inv) << 16);
      *(uint2*)&orow[dt*16] = make_uint2(u0, u1);
    }
  }
}

// ---------------- lm head prep ----------------
__global__ __launch_bounds__(256) void lmw_prep_kernel(
    const float* __restrict__ lmW, unsigned short* __restrict__ lmWt,
    float* __restrict__ lmWcol)
{
  int idx = blockIdx.x * 256 + threadIdx.x;
  int n = idx & 63, k = idx >> 6;
  lmWt[(size_t)n*Cq + k] = f2bf(lmW[(size_t)k*65 + n]);
  if (idx < Cq) lmWcol[idx] = lmW[(size_t)idx*65 + 64];
}

// ---------------- head: MFMA logits + fused log-softmax + log-sigmoid(dur) ----------------
__global__ __launch_bounds__(64) void head_mfma_kernel(
    const float* __restrict__ x, const unsigned short* __restrict__ lmWt,
    const float* __restrict__ lmWcol, const float* __restrict__ lmb,
    float* __restrict__ out)
{
  int lane = threadIdx.x;
  int lane15 = lane & 15, laneh = lane >> 4;
  int tok0 = blockIdx.x * 16;

  floatx4 acc[4];
  #pragma unroll
  for (int jt = 0; jt < 4; jt++) acc[jt] = (floatx4){0.f,0.f,0.f,0.f};

  const float* xrow = x + (size_t)(tok0 + lane15) * Cq + laneh*8;
  const unsigned short* brow = lmWt + (size_t)lane15 * Cq + laneh*8;

  for (int k0 = 0; k0 < Cq; k0 += 32) {
    float4 a0 = *(const float4*)(xrow + k0);
    float4 a1 = *(const float4*)(xrow + k0 + 4);
    bf16x8 af;
    af[0] = (__bf16)a0.x; af[1] = (__bf16)a0.y; af[2] = (__bf16)a0.z; af[3] = (__bf16)a0.w;
    af[4] = (__bf16)a1.x; af[5] = (__bf16)a1.y; af[6] = (__bf16)a1.z; af[7] = (__bf16)a1.w;
    #pragma unroll
    for (int jt = 0; jt < 4; jt++) {
      bf16x8 bfv = *(const bf16x8*)(brow + (size_t)jt*16*Cq + k0);
      acc[jt] = __builtin_amdgcn_mfma_f32_16x16x32_bf16(af, bfv, acc[jt], 0, 0, 0);
    }
  }
  #pragma unroll
  for (int jt = 0; jt < 4; jt++) {
    float bias = lmb[jt*16 + lane15];
    #pragma unroll
    for (int r = 0; r < 4; r++) acc[jt][r] += bias;
  }
  #pragma unroll
  for (int r = 0; r < 4; r++) {
    float m = fmaxf(fmaxf(acc[0][r], acc[1][r]), fmaxf(acc[2][r], acc[3][r]));
    #pragma unroll
    for (int s = 1; s < 16; s <<= 1) m = fmaxf(m, __shfl_xor(m, s, 64));
    float se = 0.f;
    #pragma unroll
    for (int jt = 0; jt < 4; jt++) se += expf(acc[jt][r] - m);
    #pragma unroll
    for (int s = 1; s < 16; s <<= 1) se += __shfl_xor(se, s, 64);
    float lse = m + logf(se);
    int tok = tok0 + laneh*4 + r;
    float* orow = out + (size_t)tok * 65;
    #pragma unroll
    for (int jt = 0; jt < 4; jt++)
      orow[jt*16 + lane15] = acc[jt][r] - lse;
  }
  int t = lane >> 2, kq = (lane & 3) * 256;
  const float* xr2 = x + (size_t)(tok0 + t) * Cq + kq;
  const float* wc = lmWcol + kq;
  float s = 0.f;
  #pragma unroll 4
  for (int i = 0; i < 256; i += 4) {
    float4 xv = *(const float4*)(xr2 + i);
    float4 wv = *(const float4*)(wc + i);
    s += xv.x*wv.x + xv.y*wv.y + xv.z*wv.z + xv.w*wv.w;
  }
  s += __shfl_xor(s, 1, 64);
  s += __shfl_xor(s, 2, 64);
  if ((lane & 3) == 0) {
    float z = s + lmb[64];
    float ls = (z >= 0.f) ? -log1pf(expf(-z)) : (z - log1pf(expf(z)));
    out[(size_t)(tok0 + t) * 65 + 64] = ls;
  }
}

extern "C" void kernel_launch(void* const* d_in, const int* in_sizes, int n_in,
                              void* d_out, int out_size, void* d_ws, size_t ws_size,
                              hipStream_t stream) {
  const int*   acts = (const int*)  d_in[0];
  const float* dur  = (const float*)d_in[1];
  const float* emb  = (const float*)d_in[2];
  const float* pos  = (const float*)d_in[3];
  const float* Wq   = (const float*)d_in[4];
  const float* Wk   = (const float*)d_in[5];
  const float* Wv   = (const float*)d_in[6];
  const float* Wo   = (const float*)d_in[7];
  const float* bo   = (const float*)d_in[8];
  const float* W1   = (const float*)d_in[9];
  const float* b1   = (const float*)d_in[10];
  const float* W2   = (const float*)d_in[11];
  const float* b2   = (const float*)d_in[12];
  const float* g1   = (const float*)d_in[13];
  const float* g2   = (const float*)d_in[14];
  const float* lmW  = (const float*)d_in[15];
  const float* lmb  = (const float*)d_in[16];
  float* out = (float*)d_out;
  (void)in_sizes; (void)n_in; (void)out_size; (void)ws_size;

  char* w = (char*)d_ws;
  auto take = [&](size_t bytes) { char* p = w; w += (bytes + 255) & ~(size_t)255; return p; };
  unsigned short* qk  = (unsigned short*)take((size_t)BT*2048*2);
  unsigned short* vT  = (unsigned short*)take((size_t)Bq*Hq*Dq*Tq*2);
  unsigned short* ob  = (unsigned short*)take((size_t)BT*Cq*2);
  unsigned short* m1  = qk;                      // FF1 out aliases qk+vT+ob (32 MB)
  unsigned short* hb  = (unsigned short*)take((size_t)BT*Cq*2);
  float*          x   = (float*)take((size_t)BT*Cq*4);
  unsigned short* wqkvl = (unsigned short*)take((size_t)3072*Cq*2);
  unsigned short* wol   = (unsigned short*)take((size_t)Cq*Cq*2);
  unsigned short* w1l   = (unsigned short*)take((size_t)Fq*Cq*2);
  unsigned short* w2l   = (unsigned short*)take((size_t)Cq*Fq*2);
  unsigned short* lmWt  = (unsigned short*)take((size_t)64*Cq*2);
  float*          lmWcol= (float*)take((size_t)Cq*4);
  float*          part  = (float*)take((size_t)2*BT*Cq*4);   // split-K partials (32 MB)

  dim3 tb(32, 8);
  embed_kernel<<<BT, 256, 0, stream>>>(acts, dur, emb, pos, x);
  lmw_prep_kernel<<<256, 256, 0, stream>>>(lmW, lmWt, lmWcol);

  for (int l = 0; l < Lq; l++) {
    prep_layer_kernel<<<12288, tb, 0, stream>>>(
        Wq + (size_t)l*Hq*Cq*Dq, Wk + (size_t)l*Hq*Cq*Dq, Wv + (size_t)l*Hq*Cq*Dq,
        Wo + (size_t)l*Cq*Cq, W1 + (size_t)l*Cq*Fq, W2 + (size_t)l*Fq*Cq,
        wqkvl, wol, w1l, w2l);

    rmsnorm_kernel<<<BT, 256, 0, stream>>>(x, g1 + l*Cq, hb);
    gemm_bt_kernel<0><<<dim3(24,32), 256, 0, stream>>>(
        hb, Cq, wqkvl, Cq, Cq, qk, 2048, vT, nullptr, 0, nullptr);
    attn_kernel<<<Bq*Hq*8, 256, 0, stream>>>(qk, vT, ob);
    gemm_bt_kernel<2><<<dim3(8,32), 256, 0, stream>>>(
        ob, Cq, wol, Cq, Cq, nullptr, 0, nullptr, x, Cq, bo + l*Cq);
    rmsnorm_kernel<<<BT, 256, 0, stream>>>(x, g2 + l*Cq, hb);
    gemm256r_kernel<<<dim3(16,16), 512, 0, stream>>>(
        hb, Cq, w1l, Cq, Cq, m1, Fq, b1 + l*Fq);
    gemm_bt_kernel<3><<<dim3(8,32,2), 256, 0, stream>>>(
        m1, Fq, w2l, Fq, 2048, nullptr, 0, nullptr, part, Cq, nullptr);
    splitk_reduce_kernel<<<BT*Cq/1024, 256, 0, stream>>>(part, x, b2 + l*Cq);
  }
  head_mfma_kernel<<<BT/16, 64, 0, stream>>>(x, lmWt, lmWcol, lmb, out);
}

// Round 7
// 1127.310 us; speedup vs baseline: 1.1136x; 1.0439x over previous
//
#include <hip/hip_runtime.h>

// Problem constants
#define Bq 4
#define Tq 1024
#define Cq 1024
#define Hq 16
#define Dq 64
#define Fq 4096
#define Lq 4
#define BT (Bq*Tq)

typedef __attribute__((ext_vector_type(8))) __bf16 bf16x8;
typedef __attribute__((ext_vector_type(4))) float  floatx4;

__device__ __forceinline__ unsigned short f2bf(float f) {
  unsigned int u = __builtin_bit_cast(unsigned int, f);
  u = (u + 0x7FFFu + ((u >> 16) & 1u)) >> 16;   // RNE
  return (unsigned short)u;
}
__device__ __forceinline__ float bf2f(unsigned short u) {
  unsigned int x = ((unsigned int)u) << 16;
  return __builtin_bit_cast(float, x);
}

// async global->LDS, 16B per lane; lds ptr must be wave-uniform (HW adds lane*16)
__device__ __forceinline__ void gld_lds16(const void* g, void* lds) {
  __builtin_amdgcn_global_load_lds(
      (const __attribute__((address_space(1))) unsigned int*)g,
      (__attribute__((address_space(3))) unsigned int*)lds, 16, 0, 0);
}

// partial-drain barrier used by the legacy 128^2 kernel (measured-good)
__device__ __forceinline__ void barrier_vmcnt4() {
  asm volatile("s_waitcnt vmcnt(4)\n\ts_barrier" ::: "memory");
}

// full LDS-sync barrier for the 256^2 kernel: drain this wave's LDS ops,
// then barrier => at each barrier every wave's phase reads AND writes are
// retired. "memory" clobber gives IR-level ordering; sched_barrier(0) pins
// the machine scheduler (rule #18).
__device__ __forceinline__ void tbar_lds() {
  __builtin_amdgcn_sched_barrier(0);
  asm volatile("s_waitcnt lgkmcnt(0)\n\ts_barrier" ::: "memory");
  __builtin_amdgcn_sched_barrier(0);
}

// ---------------- embed: x = concat(emb[acts], dur) + pos ----------------
__global__ __launch_bounds__(256) void embed_kernel(
    const int* __restrict__ acts, const float* __restrict__ dur,
    const float* __restrict__ emb, const float* __restrict__ pos,
    float* __restrict__ x)
{
  int tok = blockIdx.x;
  int t = tok & (Tq-1);
  int a = acts[tok];
  const float* er = emb + (size_t)a * (Cq-1);
  const float* pr = pos + (size_t)t * Cq;
  float* xr = x + (size_t)tok * Cq;
  float dv = dur[tok];
  for (int c = threadIdx.x; c < Cq; c += 256) {
    float v = (c < Cq-1) ? er[c] : dv;
    xr[c] = v + pr[c];
  }
}

// ---------------- rmsnorm -> bf16 ----------------
__global__ __launch_bounds__(256) void rmsnorm_kernel(
    const float* __restrict__ x, const float* __restrict__ g,
    unsigned short* __restrict__ h)
{
  int tok = blockIdx.x, tid = threadIdx.x;
  const float4* xr = (const float4*)(x + (size_t)tok * Cq);
  float4 v = xr[tid];
  float ss = v.x*v.x + v.y*v.y + v.z*v.z + v.w*v.w;
  #pragma unroll
  for (int s = 32; s >= 1; s >>= 1) ss += __shfl_xor(ss, s, 64);
  __shared__ float ws4[4];
  if ((tid & 63) == 0) ws4[tid >> 6] = ss;
  __syncthreads();
  float tot = ws4[0] + ws4[1] + ws4[2] + ws4[3];
  float r = rsqrtf(tot * (1.0f/(float)Cq) + 1.1920928955078125e-07f);
  float4 gv = ((const float4*)g)[tid];
  unsigned short o4[4] = { f2bf(v.x*r*gv.x), f2bf(v.y*r*gv.y),
                           f2bf(v.z*r*gv.z), f2bf(v.w*r*gv.w) };
  *(uint2*)(h + (size_t)tok*Cq + tid*4) = *(const uint2*)o4;
}

// ---------------- fused per-layer weight prep: all 6 transposes in 1 launch ----------------
__global__ void prep_layer_kernel(
    const float* __restrict__ Wq, const float* __restrict__ Wk,
    const float* __restrict__ Wv, const float* __restrict__ Wo,
    const float* __restrict__ W1, const float* __restrict__ W2,
    unsigned short* __restrict__ wqkvl, unsigned short* __restrict__ wol,
    unsigned short* __restrict__ w1l,   unsigned short* __restrict__ w2l)
{
  __shared__ float tile[32][33];
  int z = blockIdx.x;
  const float* in; unsigned short* out;
  int R, Cc, tx, ty;
  if (z < 3072) {
    int i = z >> 10, t = z & 1023;
    int hh = t >> 6, rem = t & 63;
    ty = rem >> 1; tx = rem & 1;
    const float* w = (i == 0) ? Wq : (i == 1) ? Wk : Wv;
    in = w + (size_t)hh * Cq * Dq;
    out = wqkvl + (size_t)i * 1024 * 1024 + (size_t)hh * 64 * 1024;
    R = 1024; Cc = 64;
  } else if (z < 4096) {
    int t = z - 3072;
    tx = t & 31; ty = t >> 5;
    in = Wo; out = wol; R = 1024; Cc = 1024;
  } else if (z < 8192) {
    int t = z - 4096;
    tx = t & 127; ty = t >> 7;
    in = W1; out = w1l; R = 1024; Cc = 4096;
  } else {
    int t = z - 8192;
    tx = t & 31; ty = t >> 5;
    in = W2; out = w2l; R = 4096; Cc = 1024;
  }
  int c0 = tx * 32, r0 = ty * 32;
  int lx = threadIdx.x, ly = threadIdx.y;  // 32 x 8
  #pragma unroll
  for (int i = 0; i < 32; i += 8)
    tile[ly+i][lx] = in[(size_t)(r0+ly+i)*Cc + c0 + lx];
  __syncthreads();
  #pragma unroll
  for (int i = 0; i < 32; i += 8)
    out[(size_t)(c0+ly+i)*R + r0 + lx] = f2bf(tile[lx][ly+i]);
}

// ---------------- legacy 128^2 GEMM (QKV: EPI 0, Wo: EPI 2) ----------------
template <int EPI>
__global__ __launch_bounds__(256)
void gemm_bt_kernel(const unsigned short* __restrict__ A, int lda,
                    const unsigned short* __restrict__ Bt, int ldb,
                    int KS,
                    unsigned short* __restrict__ outB, int ldc,
                    unsigned short* __restrict__ vT,
                    float* __restrict__ outF, int ldf,
                    const float* __restrict__ bias)
{
  __shared__ unsigned short lds_a[3*4096];
  __shared__ unsigned short lds_b[3*4096];
  int tid = threadIdx.x;
  int lane = tid & 63, wv = tid >> 6;
  int lane15 = lane & 15, laneh = lane >> 4;
  int m0 = blockIdx.y * 128, n0 = blockIdx.x * 128;
  int wm = wv & 1, wn = wv >> 1;

  floatx4 acc[4][4];
  #pragma unroll
  for (int i = 0; i < 4; i++)
    #pragma unroll
    for (int j = 0; j < 4; j++) acc[i][j] = (floatx4){0.f,0.f,0.f,0.f};

  int seg0 = (wv*2+0)*64 + lane;
  int seg1 = (wv*2+1)*64 + lane;
  int ra0 = seg0 >> 2, ca0 = ((seg0 & 3) ^ (ra0 & 3)) * 8;
  int ra1 = seg1 >> 2, ca1 = ((seg1 & 3) ^ (ra1 & 3)) * 8;
  const unsigned short* a_src0 = A  + (size_t)(m0+ra0)*lda + ca0;
  const unsigned short* a_src1 = A  + (size_t)(m0+ra1)*lda + ca1;
  const unsigned short* b_src0 = Bt + (size_t)(n0+ra0)*ldb + ca0;
  const unsigned short* b_src1 = Bt + (size_t)(n0+ra1)*ldb + ca1;
  unsigned short* a_dst0 = &lds_a[(wv*2+0)*512];
  unsigned short* a_dst1 = &lds_a[(wv*2+1)*512];
  unsigned short* b_dst0 = &lds_b[(wv*2+0)*512];
  unsigned short* b_dst1 = &lds_b[(wv*2+1)*512];

  int sx = (laneh ^ (lane15 & 3)) * 8;

  int kbeg = 0;
  int nIter = KS >> 5;

  auto stage = [&](int k0, int buf) {
    int off = buf * 4096;
    gld_lds16(a_src0 + k0, a_dst0 + off);
    gld_lds16(a_src1 + k0, a_dst1 + off);
    gld_lds16(b_src0 + k0, b_dst0 + off);
    gld_lds16(b_src1 + k0, b_dst1 + off);
  };

  stage(kbeg, 0);
  stage(kbeg + 32, 1);
  int cb = 0, pb = 2;
  for (int it = 0; it < nIter; ++it) {
    barrier_vmcnt4();
    if (it + 2 < nIter) stage(kbeg + (it+2)*32, pb);
    const unsigned short* la = &lds_a[cb*4096];
    const unsigned short* lb = &lds_b[cb*4096];
    bf16x8 af[4], bf[4];
    #pragma unroll
    for (int i = 0; i < 4; i++)
      af[i] = *(const bf16x8*)&la[(wm*64 + i*16 + lane15)*32 + sx];
    #pragma unroll
    for (int j = 0; j < 4; j++)
      bf[j] = *(const bf16x8*)&lb[(wn*64 + j*16 + lane15)*32 + sx];
    #pragma unroll
    for (int i = 0; i < 4; i++)
      #pragma unroll
      for (int j = 0; j < 4; j++)
        acc[i][j] = __builtin_amdgcn_mfma_f32_16x16x32_bf16(af[i], bf[j], acc[i][j], 0, 0, 0);
    cb = (cb == 2) ? 0 : cb + 1;
    pb = (pb == 2) ? 0 : pb + 1;
  }

  #pragma unroll
  for (int i = 0; i < 4; i++) {
    int row = m0 + wm*64 + i*16 + laneh*4;
    #pragma unroll
    for (int j = 0; j < 4; j++) {
      int col = n0 + wn*64 + j*16 + lane15;
      #pragma unroll
      for (int r = 0; r < 4; r++) {
        float v = acc[i][j][r];
        int rr = row + r;
        if constexpr (EPI == 0) {
          if (col < 2048) {
            outB[(size_t)rr*ldc + col] = f2bf(v);
          } else {
            int b = rr >> 10, t = rr & (Tq-1);
            int hd = col - 2048, hh = hd >> 6, d = hd & 63;
            vT[(((size_t)b*Hq + hh)*Dq + d)*Tq + t] = f2bf(v);
          }
        } else {
          outF[(size_t)rr*ldf + col] += v + bias[col];
        }
      }
    }
  }
}

// ---------------- 256^2 4-phase GEMM, reg-staged (r6-verified structure) ----
// EPI 1: gelu->bf16 (FF1). EPI 3: bf16 split-K partial (FF2, kbeg=z*KS).
// Loop/staging/barrier schedule byte-identical to the round-6 verified kernel;
// only kbeg and the epilogue differ per EPI. See r6 comments for the region
// race ledger and the (fixed) prologue that stages tile0 fully + tile1's
// A-lo/B-hi/A-hi into buf1.
template <int EPI>
__global__ __launch_bounds__(512, 2)
void gemm256r_kernel(const unsigned short* __restrict__ A, int lda,
                     const unsigned short* __restrict__ Bt, int ldb,
                     int KS,
                     unsigned short* __restrict__ outB, int ldc,
                     const float* __restrict__ bias)
{
  __shared__ unsigned short lds_a[2][256*64];
  __shared__ unsigned short lds_b[2][256*64];
  const int tid = threadIdx.x;
  const int lane = tid & 63, wv = tid >> 6;
  const int lane15 = lane & 15, laneh = lane >> 4;
  const int wm = wv & 1, wn = wv >> 1;      // 2 x 4 waves

  const int m0 = (int)blockIdx.y * 256, n0 = (int)blockIdx.x * 256;
  const int kbeg = (EPI == 3) ? (int)blockIdx.z * KS : 0;
  const int nT = KS >> 6;

  const int rowS = tid >> 3;
  const int gS  = tid & 7;
  const int swz = (gS ^ (rowS & 7)) * 8;    // write-side XOR swizzle

  auto ldA = [&](int kt, int h, bf16x8& r0, bf16x8& r1) {
    const unsigned short* s = A + (size_t)(m0 + h*128 + rowS)*lda + kbeg + kt*64 + gS*8;
    r0 = *(const bf16x8*)s;
    r1 = *(const bf16x8*)(s + (size_t)64*lda);
  };
  auto ldB = [&](int kt, int h, bf16x8& r0, bf16x8& r1) {
    const unsigned short* s = Bt + (size_t)(n0 + h*128 + rowS)*ldb + kbeg + kt*64 + gS*8;
    r0 = *(const bf16x8*)s;
    r1 = *(const bf16x8*)(s + (size_t)64*ldb);
  };
  auto wrA = [&](int h, int b, bf16x8 r0, bf16x8 r1) {
    unsigned short* d = &lds_a[b][(h*128 + rowS)*64 + swz];
    *(bf16x8*)d = r0;
    *(bf16x8*)(d + 64*64) = r1;   // row+64: same (row&7) => same swizzle
  };
  auto wrB = [&](int h, int b, bf16x8 r0, bf16x8 r1) {
    unsigned short* d = &lds_b[b][(h*128 + rowS)*64 + swz];
    *(bf16x8*)d = r0;
    *(bf16x8*)(d + 64*64) = r1;
  };

  const int soff0 = ((laneh)     ^ (lane15 & 7)) * 8;   // ks=0 granules 0..3
  const int soff1 = ((4 + laneh) ^ (lane15 & 7)) * 8;   // ks=1 granules 4..7
  const int arow = (wm*16 + lane15) * 64;
  const int brow = (wn*16 + lane15) * 64;

  floatx4 acc[8][4];
  #pragma unroll
  for (int i = 0; i < 8; i++)
    #pragma unroll
    for (int j = 0; j < 4; j++) acc[i][j] = (floatx4){0.f,0.f,0.f,0.f};

  bf16x8 af[4][2], bfr[2][2];
  bf16x8 sX0, sX1, sY0, sY1;

  // prologue: tile0 -> buf0 (all), tile1 A-lo/B-hi/A-hi -> buf1,
  // then prime sX = B-lo(1), sY = A-lo(2).
  ldA(0, 0, sX0, sX1); ldB(0, 0, sY0, sY1);
  wrA(0, 0, sX0, sX1); wrB(0, 0, sY0, sY1);
  ldA(0, 1, sX0, sX1); ldB(0, 1, sY0, sY1);
  wrA(1, 0, sX0, sX1); wrB(1, 0, sY0, sY1);
  if (nT > 1) {
    ldA(1, 0, sX0, sX1); ldB(1, 1, sY0, sY1);
    wrA(0, 1, sX0, sX1); wrB(1, 1, sY0, sY1);
    ldA(1, 1, sX0, sX1);
    wrA(1, 1, sX0, sX1);
    ldB(1, 0, sX0, sX1);               // prime sX = B-lo(1)
  }
  if (nT > 2) ldA(2, 0, sY0, sY1);     // prime sY = A-lo(2)
  tbar_lds();

  for (int t = 0; t < nT; ++t) {
    const int buf = t & 1;
    const unsigned short* la = &lds_a[buf][0];
    const unsigned short* lb = &lds_b[buf][0];

    // ---- P1: (A-lo, B-lo) ----
    #pragma unroll
    for (int ii = 0; ii < 4; ii++) {
      af[ii][0] = *(const bf16x8*)&la[arow + ii*2048 + soff0];
      af[ii][1] = *(const bf16x8*)&la[arow + ii*2048 + soff1];
    }
    #pragma unroll
    for (int jj = 0; jj < 2; jj++) {
      bfr[jj][0] = *(const bf16x8*)&lb[brow + jj*4096 + soff0];
      bfr[jj][1] = *(const bf16x8*)&lb[brow + jj*4096 + soff1];
    }
    if (t + 1 < nT) wrB(0, buf^1, sX0, sX1);   // B-lo(t+1)
    if (t + 2 < nT) ldB(t+2, 1, sX0, sX1);     // B-hi(t+2) -> X
    __builtin_amdgcn_s_setprio(1);
    #pragma unroll
    for (int ks = 0; ks < 2; ks++)
      #pragma unroll
      for (int ii = 0; ii < 4; ii++)
        #pragma unroll
        for (int jj = 0; jj < 2; jj++)
          acc[ii][jj] = __builtin_amdgcn_mfma_f32_16x16x32_bf16(af[ii][ks], bfr[jj][ks], acc[ii][jj], 0, 0, 0);
    __builtin_amdgcn_s_setprio(0);
    tbar_lds();

    // ---- P2: (A-lo, B-hi) — af reused ----
    #pragma unroll
    for (int jj = 0; jj < 2; jj++) {
      bfr[jj][0] = *(const bf16x8*)&lb[8192 + brow + jj*4096 + soff0];
      bfr[jj][1] = *(const bf16x8*)&lb[8192 + brow + jj*4096 + soff1];
    }
    if (t + 2 < nT) wrA(0, buf, sY0, sY1);     // A-lo(t+2)
    if (t + 2 < nT) ldA(t+2, 1, sY0, sY1);     // A-hi(t+2) -> Y
    __builtin_amdgcn_s_setprio(1);
    #pragma unroll
    for (int ks = 0; ks < 2; ks++)
      #pragma unroll
      for (int ii = 0; ii < 4; ii++)
        #pragma unroll
        for (int jj = 0; jj < 2; jj++)
          acc[ii][2+jj] = __builtin_amdgcn_mfma_f32_16x16x32_bf16(af[ii][ks], bfr[jj][ks], acc[ii][2+jj], 0, 0, 0);
    __builtin_amdgcn_s_setprio(0);
    tbar_lds();

    // ---- P3: (A-hi, B-hi) — bfr reused ----
    #pragma unroll
    for (int ii = 0; ii < 4; ii++) {
      af[ii][0] = *(const bf16x8*)&la[8192 + arow + ii*2048 + soff0];
      af[ii][1] = *(const bf16x8*)&la[8192 + arow + ii*2048 + soff1];
    }
    if (t + 2 < nT) wrB(1, buf, sX0, sX1);     // B-hi(t+2)
    if (t + 2 < nT) ldB(t+2, 0, sX0, sX1);     // B-lo(t+2) -> X
    __builtin_amdgcn_s_setprio(1);
    #pragma unroll
    for (int ks = 0; ks < 2; ks++)
      #pragma unroll
      for (int ii = 0; ii < 4; ii++)
        #pragma unroll
        for (int jj = 0; jj < 2; jj++)
          acc[4+ii][2+jj] = __builtin_amdgcn_mfma_f32_16x16x32_bf16(af[ii][ks], bfr[jj][ks], acc[4+ii][2+jj], 0, 0, 0);
    __builtin_amdgcn_s_setprio(0);
    tbar_lds();

    // ---- P4: (A-hi, B-lo) — af reused, B-lo re-read ----
    #pragma unroll
    for (int jj = 0; jj < 2; jj++) {
      bfr[jj][0] = *(const bf16x8*)&lb[brow + jj*4096 + soff0];
      bfr[jj][1] = *(const bf16x8*)&lb[brow + jj*4096 + soff1];
    }
    if (t + 2 < nT) wrA(1, buf, sY0, sY1);     // A-hi(t+2)
    if (t + 3 < nT) ldA(t+3, 0, sY0, sY1);     // A-lo(t+3) -> Y
    __builtin_amdgcn_s_setprio(1);
    #pragma unroll
    for (int ks = 0; ks < 2; ks++)
      #pragma unroll
      for (int ii = 0; ii < 4; ii++)
        #pragma unroll
        for (int jj = 0; jj < 2; jj++)
          acc[4+ii][jj] = __builtin_amdgcn_mfma_f32_16x16x32_bf16(af[ii][ks], bfr[jj][ks], acc[4+ii][jj], 0, 0, 0);
    __builtin_amdgcn_s_setprio(0);
    tbar_lds();
  }

  unsigned short* outZ = (EPI == 3) ? outB + (size_t)blockIdx.z * BT * Cq : outB;

  #pragma unroll
  for (int i = 0; i < 8; i++) {
    int row = m0 + (i>>2)*128 + (i&3)*32 + wm*16 + laneh*4;
    #pragma unroll
    for (int j = 0; j < 4; j++) {
      int col = n0 + (j>>1)*128 + (j&1)*64 + wn*16 + lane15;
      #pragma unroll
      for (int r = 0; r < 4; r++) {
        float v = acc[i][j][r];
        int rr = row + r;
        if constexpr (EPI == 1) {
          float z = v + bias[col];
          float u = 0.79788456080286536f * (z + 0.044715f * z*z*z);
          float tt = 1.f - 2.f / (__expf(2.f*u) + 1.f);
          float gl = 0.5f * z * (1.f + tt);
          outB[(size_t)rr*ldc + col] = f2bf(gl);
        } else {
          outZ[(size_t)rr*ldc + col] = f2bf(v);   // bf16 split-K partial
        }
      }
    }
  }
}

// ---------------- split-K reduce: x += sum_z bf16 partials + bias ----------
__global__ __launch_bounds__(256) void splitk_reduce4_kernel(
    const unsigned short* __restrict__ p, float* __restrict__ x,
    const float* __restrict__ bias)
{
  const size_t S = (size_t)BT * Cq;
  size_t o = ((size_t)blockIdx.x * 256 + threadIdx.x) * 4;
  float4 xv = *(const float4*)(x + o);
  float4 bi = *(const float4*)(bias + (o & (Cq-1)));
  float s0 = 0.f, s1 = 0.f, s2 = 0.f, s3 = 0.f;
  #pragma unroll
  for (int z = 0; z < 4; z++) {
    ushort4 u = *(const ushort4*)(p + (size_t)z*S + o);
    s0 += bf2f(u.x); s1 += bf2f(u.y); s2 += bf2f(u.z); s3 += bf2f(u.w);
  }
  xv.x += s0 + bi.x;
  xv.y += s1 + bi.y;
  xv.z += s2 + bi.z;
  xv.w += s3 + bi.w;
  *(float4*)(x + o) = xv;
}

// ---------------- flash attention (causal), S^T form (R6-verified) ----------------
__global__ __launch_bounds__(256)
void attn_kernel(const unsigned short* __restrict__ qk,   // (BT,2048): q 0..1023, k 1024..2047
                 const unsigned short* __restrict__ vT,   // (B,H,D,T)
                 unsigned short* __restrict__ ob)         // (BT,1024)
{
  __shared__ unsigned short Ks [2][64*64];
  __shared__ unsigned short Vts[2][64*64];
  __shared__ unsigned short Ps [4*16*64];
  int tid = threadIdx.x, lane = tid & 63, wv = tid >> 6;
  int lane15 = lane & 15, laneh = lane >> 4;
  int blk = blockIdx.x;
  int p = blk & 7, bh = blk >> 3;
  int h = bh & (Hq-1), b = bh >> 4;
  size_t tokbase = (size_t)b * Tq;
  const unsigned short* Kbase = qk + tokbase*2048 + 1024 + h*64;
  const unsigned short* Vbase = vT + (size_t)bh * Dq * Tq;

  int so  = (laneh ^ (lane15 & 7)) * 8;
  int so32 = so ^ 32;
  unsigned short* Pw = &Ps[wv*1024];

  auto stage = [&](int j0, int buf) {
    #pragma unroll
    for (int i = 0; i < 2; i++) {
      int seg = (wv*2+i)*64 + lane;
      int row = seg >> 3;
      int col = ((seg & 7) ^ (row & 7)) * 8;
      gld_lds16(Kbase + (size_t)(j0+row)*2048 + col, &Ks [buf][(wv*2+i)*512]);
      gld_lds16(Vbase + (size_t)row*Tq + j0 + col,   &Vts[buf][(wv*2+i)*512]);
    }
  };

  for (int phase = 0; phase < 2; ++phase) {
    int qt = phase ? (15 - p) : p;
    int qrow0 = qt*64 + wv*16;
    bf16x8 qf0, qf1;
    {
      const unsigned short* qp = qk + (tokbase + qrow0 + lane15)*2048 + h*64 + laneh*8;
      qf0 = *(const bf16x8*)(qp);
      qf1 = *(const bf16x8*)(qp + 32);
    }
    floatx4 oacc[4];
    #pragma unroll
    for (int d = 0; d < 4; d++) oacc[d] = (floatx4){0.f,0.f,0.f,0.f};
    float mrow = -__builtin_inff(), lrow = 0.f;
    int nT = qt + 1;

    __syncthreads();
    stage(0, 0);
    for (int it = 0; it < nT; ++it) {
      __syncthreads();
      if (it + 1 < nT) stage((it+1)*64, (it+1) & 1);
      int buf = it & 1;
      int j0 = it*64;

      floatx4 sac[4];
      #pragma unroll
      for (int jt = 0; jt < 4; jt++) {
        int row = jt*16 + lane15;
        bf16x8 kf0 = *(const bf16x8*)&Ks[buf][row*64 + so];
        bf16x8 kf1 = *(const bf16x8*)&Ks[buf][row*64 + so32];
        sac[jt] = (floatx4){0.f,0.f,0.f,0.f};
        sac[jt] = __builtin_amdgcn_mfma_f32_16x16x32_bf16(kf0, qf0, sac[jt], 0, 0, 0);
        sac[jt] = __builtin_amdgcn_mfma_f32_16x16x32_bf16(kf1, qf1, sac[jt], 0, 0, 0);
      }
      if (j0 + 63 > qrow0) {
        int tokg = qrow0 + lane15;
        #pragma unroll
        for (int jt = 0; jt < 4; jt++)
          #pragma unroll
          for (int r = 0; r < 4; r++) {
            int kv = j0 + jt*16 + laneh*4 + r;
            sac[jt][r] = (kv <= tokg) ? sac[jt][r] * 0.125f : -__builtin_inff();
          }
      } else {
        #pragma unroll
        for (int jt = 0; jt < 4; jt++)
          #pragma unroll
          for (int r = 0; r < 4; r++) sac[jt][r] *= 0.125f;
      }
      float mx = sac[0][0];
      #pragma unroll
      for (int jt = 0; jt < 4; jt++)
        #pragma unroll
        for (int r = 0; r < 4; r++) mx = fmaxf(mx, sac[jt][r]);
      mx = fmaxf(mx, __shfl_xor(mx, 16, 64));
      mx = fmaxf(mx, __shfl_xor(mx, 32, 64));
      float mn = fmaxf(mrow, mx);
      float alpha = __expf(mrow - mn);
      float psum = 0.f;
      #pragma unroll
      for (int jt = 0; jt < 4; jt++)
        #pragma unroll
        for (int r = 0; r < 4; r++) {
          float pv = __expf(sac[jt][r] - mn);
          sac[jt][r] = pv;
          psum += pv;
        }
      psum += __shfl_xor(psum, 16, 64);
      psum += __shfl_xor(psum, 32, 64);
      lrow = lrow * alpha + psum;
      mrow = mn;
      #pragma unroll
      for (int dt = 0; dt < 4; dt++)
        #pragma unroll
        for (int r = 0; r < 4; r++) oacc[dt][r] *= alpha;

      #pragma unroll
      for (int jt = 0; jt < 4; jt++) {
        unsigned int p0 = (unsigned int)f2bf(sac[jt][0]) | ((unsigned int)f2bf(sac[jt][1]) << 16);
        unsigned int p1 = (unsigned int)f2bf(sac[jt][2]) | ((unsigned int)f2bf(sac[jt][3]) << 16);
        int slot = (jt*2 + (laneh >> 1)) ^ (lane15 & 7);
        *(uint2*)&Pw[lane15*64 + slot*8 + (laneh & 1)*4] = make_uint2(p0, p1);
      }
      bf16x8 pf0 = *(const bf16x8*)&Pw[lane15*64 + so];
      bf16x8 pf1 = *(const bf16x8*)&Pw[lane15*64 + so32];
      #pragma unroll
      for (int dt = 0; dt < 4; dt++) {
        int row = dt*16 + lane15;
        bf16x8 vf0 = *(const bf16x8*)&Vts[buf][row*64 + so];
        bf16x8 vf1 = *(const bf16x8*)&Vts[buf][row*64 + so32];
        oacc[dt] = __builtin_amdgcn_mfma_f32_16x16x32_bf16(vf0, pf0, oacc[dt], 0, 0, 0);
        oacc[dt] = __builtin_amdgcn_mfma_f32_16x16x32_bf16(vf1, pf1, oacc[dt], 0, 0, 0);
      }
    }
    float inv = 1.f / lrow;
    unsigned short* orow = ob + (tokbase + qrow0 + lane15)*Cq + h*64 + laneh*4;
    #pragma unroll
    for (int dt = 0; dt < 4; dt++) {
      unsigned int u0 = (unsigned int)f2bf(oacc[dt][0]*inv) | ((unsigned int)f2bf(oacc[dt][1]*inv) << 16);
      unsigned int u1 = (unsigned int)f2bf(oacc[dt][2]*inv) | ((unsigned int)f2bf(oacc[dt][3]*inv) << 16);
      *(uint2*)&orow[dt*16] = make_uint2(u0, u1);
    }
  }
}

// ---------------- lm head prep ----------------
__global__ __launch_bounds__(256) void lmw_prep_kernel(
    const float* __restrict__ lmW, unsigned short* __restrict__ lmWt,
    float* __restrict__ lmWcol)
{
  int idx = blockIdx.x * 256 + threadIdx.x;
  int n = idx & 63, k = idx >> 6;
  lmWt[(size_t)n*Cq + k] = f2bf(lmW[(size_t)k*65 + n]);
  if (idx < Cq) lmWcol[idx] = lmW[(size_t)idx*65 + 64];
}

// ---------------- head: MFMA logits + fused log-softmax + log-sigmoid(dur) ----------------
__global__ __launch_bounds__(64) void head_mfma_kernel(
    const float* __restrict__ x, const unsigned short* __restrict__ lmWt,
    const float* __restrict__ lmWcol, const float* __restrict__ lmb,
    float* __restrict__ out)
{
  int lane = threadIdx.x;
  int lane15 = lane & 15, laneh = lane >> 4;
  int tok0 = blockIdx.x * 16;

  floatx4 acc[4];
  #pragma unroll
  for (int jt = 0; jt < 4; jt++) acc[jt] = (floatx4){0.f,0.f,0.f,0.f};

  const float* xrow = x + (size_t)(tok0 + lane15) * Cq + laneh*8;
  const unsigned short* brow = lmWt + (size_t)lane15 * Cq + laneh*8;

  for (int k0 = 0; k0 < Cq; k0 += 32) {
    float4 a0 = *(const float4*)(xrow + k0);
    float4 a1 = *(const float4*)(xrow + k0 + 4);
    bf16x8 af;
    af[0] = (__bf16)a0.x; af[1] = (__bf16)a0.y; af[2] = (__bf16)a0.z; af[3] = (__bf16)a0.w;
    af[4] = (__bf16)a1.x; af[5] = (__bf16)a1.y; af[6] = (__bf16)a1.z; af[7] = (__bf16)a1.w;
    #pragma unroll
    for (int jt = 0; jt < 4; jt++) {
      bf16x8 bfv = *(const bf16x8*)(brow + (size_t)jt*16*Cq + k0);
      acc[jt] = __builtin_amdgcn_mfma_f32_16x16x32_bf16(af, bfv, acc[jt], 0, 0, 0);
    }
  }
  #pragma unroll
  for (int jt = 0; jt < 4; jt++) {
    float bias = lmb[jt*16 + lane15];
    #pragma unroll
    for (int r = 0; r < 4; r++) acc[jt][r] += bias;
  }
  #pragma unroll
  for (int r = 0; r < 4; r++) {
    float m = fmaxf(fmaxf(acc[0][r], acc[1][r]), fmaxf(acc[2][r], acc[3][r]));
    #pragma unroll
    for (int s = 1; s < 16; s <<= 1) m = fmaxf(m, __shfl_xor(m, s, 64));
    float se = 0.f;
    #pragma unroll
    for (int jt = 0; jt < 4; jt++) se += expf(acc[jt][r] - m);
    #pragma unroll
    for (int s = 1; s < 16; s <<= 1) se += __shfl_xor(se, s, 64);
    float lse = m + logf(se);
    int tok = tok0 + laneh*4 + r;
    float* orow = out + (size_t)tok * 65;
    #pragma unroll
    for (int jt = 0; jt < 4; jt++)
      orow[jt*16 + lane15] = acc[jt][r] - lse;
  }
  int t = lane >> 2, kq = (lane & 3) * 256;
  const float* xr2 = x + (size_t)(tok0 + t) * Cq + kq;
  const float* wc = lmWcol + kq;
  float s = 0.f;
  #pragma unroll 4
  for (int i = 0; i < 256; i += 4) {
    float4 xv = *(const float4*)(xr2 + i);
    float4 wv = *(const float4*)(wc + i);
    s += xv.x*wv.x + xv.y*wv.y + xv.z*wv.z + xv.w*wv.w;
  }
  s += __shfl_xor(s, 1, 64);
  s += __shfl_xor(s, 2, 64);
  if ((lane & 3) == 0) {
    float z = s + lmb[64];
    float ls = (z >= 0.f) ? -log1pf(expf(-z)) : (z - log1pf(expf(z)));
    out[(size_t)(tok0 + t) * 65 + 64] = ls;
  }
}

extern "C" void kernel_launch(void* const* d_in, const int* in_sizes, int n_in,
                              void* d_out, int out_size, void* d_ws, size_t ws_size,
                              hipStream_t stream) {
  const int*   acts = (const int*)  d_in[0];
  const float* dur  = (const float*)d_in[1];
  const float* emb  = (const float*)d_in[2];
  const float* pos  = (const float*)d_in[3];
  const float* Wq   = (const float*)d_in[4];
  const float* Wk   = (const float*)d_in[5];
  const float* Wv   = (const float*)d_in[6];
  const float* Wo   = (const float*)d_in[7];
  const float* bo   = (const float*)d_in[8];
  const float* W1   = (const float*)d_in[9];
  const float* b1   = (const float*)d_in[10];
  const float* W2   = (const float*)d_in[11];
  const float* b2   = (const float*)d_in[12];
  const float* g1   = (const float*)d_in[13];
  const float* g2   = (const float*)d_in[14];
  const float* lmW  = (const float*)d_in[15];
  const float* lmb  = (const float*)d_in[16];
  float* out = (float*)d_out;
  (void)in_sizes; (void)n_in; (void)out_size; (void)ws_size;

  char* w = (char*)d_ws;
  auto take = [&](size_t bytes) { char* p = w; w += (bytes + 255) & ~(size_t)255; return p; };
  unsigned short* qk  = (unsigned short*)take((size_t)BT*2048*2);
  unsigned short* vT  = (unsigned short*)take((size_t)Bq*Hq*Dq*Tq*2);
  unsigned short* ob  = (unsigned short*)take((size_t)BT*Cq*2);
  unsigned short* m1  = qk;                      // FF1 out aliases qk+vT+ob (32 MB)
  unsigned short* hb  = (unsigned short*)take((size_t)BT*Cq*2);
  float*          x   = (float*)take((size_t)BT*Cq*4);
  unsigned short* wqkvl = (unsigned short*)take((size_t)3072*Cq*2);
  unsigned short* wol   = (unsigned short*)take((size_t)Cq*Cq*2);
  unsigned short* w1l   = (unsigned short*)take((size_t)Fq*Cq*2);
  unsigned short* w2l   = (unsigned short*)take((size_t)Cq*Fq*2);
  unsigned short* lmWt  = (unsigned short*)take((size_t)64*Cq*2);
  float*          lmWcol= (float*)take((size_t)Cq*4);
  unsigned short* part  = (unsigned short*)take((size_t)4*BT*Cq*2);  // split-K4 bf16 partials (32 MB)

  dim3 tb(32, 8);
  embed_kernel<<<BT, 256, 0, stream>>>(acts, dur, emb, pos, x);
  lmw_prep_kernel<<<256, 256, 0, stream>>>(lmW, lmWt, lmWcol);

  for (int l = 0; l < Lq; l++) {
    prep_layer_kernel<<<12288, tb, 0, stream>>>(
        Wq + (size_t)l*Hq*Cq*Dq, Wk + (size_t)l*Hq*Cq*Dq, Wv + (size_t)l*Hq*Cq*Dq,
        Wo + (size_t)l*Cq*Cq, W1 + (size_t)l*Cq*Fq, W2 + (size_t)l*Fq*Cq,
        wqkvl, wol, w1l, w2l);

    rmsnorm_kernel<<<BT, 256, 0, stream>>>(x, g1 + l*Cq, hb);
    gemm_bt_kernel<0><<<dim3(24,32), 256, 0, stream>>>(
        hb, Cq, wqkvl, Cq, Cq, qk, 2048, vT, nullptr, 0, nullptr);
    attn_kernel<<<Bq*Hq*8, 256, 0, stream>>>(qk, vT, ob);
    gemm_bt_kernel<2><<<dim3(8,32), 256, 0, stream>>>(
        ob, Cq, wol, Cq, Cq, nullptr, 0, nullptr, x, Cq, bo + l*Cq);
    rmsnorm_kernel<<<BT, 256, 0, stream>>>(x, g2 + l*Cq, hb);
    gemm256r_kernel<1><<<dim3(16,16), 512, 0, stream>>>(
        hb, Cq, w1l, Cq, Cq, m1, Fq, b1 + l*Fq);
    gemm256r_kernel<3><<<dim3(4,16,4), 512, 0, stream>>>(
        m1, Fq, w2l, Fq, 1024, part, Cq, nullptr);
    splitk_reduce4_kernel<<<BT*Cq/1024, 256, 0, stream>>>(part, x, b2 + l*Cq);
  }
  head_mfma_kernel<<<BT/16, 64, 0, stream>>>(x, lmWt, lmWcol, lmb, out);
}